// Round 17
// baseline (330.354 us; speedup 1.0000x reference)
//
#include <hip/hip_runtime.h>
#include <cstddef>

#define NB 2048
#define NT 256

#define SD  20
#define SPH 12
#define SG  20

#define WS_KSTRIDE 192
#define WS_LD2     49152
#define WS_SSQ     49168
#define WS_G       51216
#define WS_CB      51344
#define WS_TCONV   51376

#define CONV_EPS 1e-4f

#define WFENCE() __builtin_amdgcn_wave_barrier()

#define OFF_MU 0
#define OFF_V  8388608
#define OFF_LOGP 142606336
#define OFF_Y  142606337
#define OFF_VY 146800641

__device__ __forceinline__ float lane_bcast(float v, int k) {
    return __int_as_float(__builtin_amdgcn_readlane(__float_as_int(v), k));
}

// native vector type for nontemporal builtins (HIP float4 is a class type)
typedef float nfloat4 __attribute__((ext_vector_type(4)));

__device__ __forceinline__ void ntstore4(float* p, float4 v) {
    nfloat4 nv; nv.x = v.x; nv.y = v.y; nv.z = v.z; nv.w = v.w;
    __builtin_nontemporal_store(nv, (nfloat4*)p);
}
__device__ __forceinline__ void ntstore1(float* p, float v) {
    __builtin_nontemporal_store(v, p);
}

// ---------------- Phase 1: batch-invariant Riccati recursion (1 block) -----
__launch_bounds__(64)
__global__ void cov_kernel(const float* __restrict__ gP0, const float* __restrict__ gA,
                           const float* __restrict__ gBm, const float* __restrict__ gC,
                           const float* __restrict__ gSx, const float* __restrict__ gSy,
                           float* __restrict__ out, float* __restrict__ ws)
{
    const int l  = threadIdx.x;
    const int j  = l & 15;
    const int q  = l >> 4;
    const int m8 = l >> 3;
    const int n8 = l & 7;

    __shared__ __align__(16) float sA[16*SD];
    __shared__ __align__(16) float sC[128];
    __shared__ __align__(16) float sG[8*SG];
    __shared__ __align__(16) float sW[16*8];
    __shared__ __align__(16) float sV[16*SD];
    __shared__ __align__(16) float sZ[16*SD];
    __shared__ __align__(16) float sP[16*SD];
    __shared__ __align__(16) float sCP[8*SD];
    __shared__ __align__(16) float sU[16*8];
    __shared__ __align__(16) float sPH[16*SPH];
    __shared__ __align__(16) float sSinv[64];

    {
        int r = l >> 2, c4 = l & 3;
        *(float4*)(sA + r*SD + c4*4) = *(const float4*)(gA + r*16 + c4*4);
        if (l < 32) *(float4*)(sC + l*4) = *(const float4*)(gC + l*4);
    }

    float a_row[16];
    #pragma unroll
    for (int k4 = 0; k4 < 4; ++k4) {
        float4 t4 = *(const float4*)(gA + j*16 + k4*4);
        a_row[k4*4+0]=t4.x; a_row[k4*4+1]=t4.y; a_row[k4*4+2]=t4.z; a_row[k4*4+3]=t4.w;
    }
    float4 sxr = *(const float4*)(gSx + j*16 + q*4);
    float  syr = gSy[l];

    WFENCE();

    float c_row[16];
    #pragma unroll
    for (int k4 = 0; k4 < 4; ++k4) {
        float4 cv = *(const float4*)(sC + m8*16 + k4*4);
        c_row[k4*4+0]=cv.x; c_row[k4*4+1]=cv.y; c_row[k4*4+2]=cv.z; c_row[k4*4+3]=cv.w;
    }

    {
        float g1 = 0.f, g2 = 0.f;
        #pragma unroll
        for (int i = 0; i < 16; ++i) {
            g1 += c_row[i]*sA[i*SD + n8];
            g2 += c_row[i]*sA[i*SD + n8 + 8];
        }
        sG[m8*SG + n8]     = g1;
        sG[m8*SG + n8 + 8] = g2;
        ws[WS_G + m8*16 + n8]     = g1;
        ws[WS_G + m8*16 + n8 + 8] = g2;

        if (l < 32) {
            int m = l >> 2, c = l & 3;
            float acc = 0.f;
            #pragma unroll
            for (int i = 0; i < 16; ++i) acc += sC[m*16 + i] * gBm[i*4 + c];
            ws[WS_CB + m*4 + c] = acc;
        }

        float qrow[16];
        #pragma unroll
        for (int k4 = 0; k4 < 4; ++k4) {
            float4 qv = *(const float4*)(gSx + j*16 + k4*4);
            qrow[k4*4+0]=qv.x; qrow[k4*4+1]=qv.y; qrow[k4*4+2]=qv.z; qrow[k4*4+3]=qv.w;
        }
        float w0 = 0.f, w1 = 0.f;
        #pragma unroll
        for (int k = 0; k < 16; ++k) {
            w0 += qrow[k]*sC[(2*q)*16 + k];
            w1 += qrow[k]*sC[(2*q+1)*16 + k];
        }
        sW[j*8 + 2*q]     = w0;
        sW[j*8 + 2*q + 1] = w1;
    }
    WFENCE();

    float sy0 = syr;
    #pragma unroll
    for (int k = 0; k < 16; ++k) sy0 += c_row[k]*sW[k*8 + n8];

    float g_row[16];
    #pragma unroll
    for (int k4 = 0; k4 < 4; ++k4) {
        float4 gv = *(const float4*)(sG + m8*SG + k4*4);
        g_row[k4*4+0]=gv.x; g_row[k4*4+1]=gv.y; g_row[k4*4+2]=gv.z; g_row[k4*4+3]=gv.w;
    }
    float wj0 = sW[j*8 + 2*q], wj1 = sW[j*8 + 2*q + 1];

    float acc_ld2 = 0.f;
    float pr[4];
    int   convcnt = 0;
    int   tconv   = NT-1;

    #pragma unroll 1
    for (int t = 0; t < NT; ++t) {
        float s;
        float v_row[16];

        if (t == 0) {
            float4 p0 = *(const float4*)(gP0 + j*16 + q*4);
            pr[0]=p0.x; pr[1]=p0.y; pr[2]=p0.z; pr[3]=p0.w;
            *(float4*)(sP + j*SD + q*4) = p0;
            WFENCE();
            float p_row[16];
            #pragma unroll
            for (int k4 = 0; k4 < 4; ++k4) {
                float4 pv = *(const float4*)(sP + j*SD + k4*4);
                p_row[k4*4+0]=pv.x; p_row[k4*4+1]=pv.y; p_row[k4*4+2]=pv.z; p_row[k4*4+3]=pv.w;
            }
            float ph0=0.f, ph1=0.f;
            #pragma unroll
            for (int k = 0; k < 16; ++k) {
                ph0 += p_row[k]*sC[(2*q)*16 + k];
                ph1 += p_row[k]*sC[(2*q+1)*16 + k];
            }
            *(float2*)(sPH + j*SPH + 2*q) = make_float2(ph0, ph1);
            WFENCE();
            s = syr;
            #pragma unroll
            for (int k = 0; k < 16; ++k) s += c_row[k]*sPH[k*SPH + n8];
        } else {
            #pragma unroll
            for (int k4 = 0; k4 < 4; ++k4) {
                float4 vv = *(const float4*)(sV + j*SD + k4*4);
                v_row[k4*4+0]=vv.x; v_row[k4*4+1]=vv.y; v_row[k4*4+2]=vv.z; v_row[k4*4+3]=vv.w;
            }
            float u0 = 0.f, u1 = 0.f;
            #pragma unroll
            for (int k4 = 0; k4 < 4; ++k4) {
                float4 ga = *(const float4*)(sG + (2*q)*SG + k4*4);
                float4 gb = *(const float4*)(sG + (2*q+1)*SG + k4*4);
                u0 += v_row[k4*4+0]*ga.x + v_row[k4*4+1]*ga.y
                    + v_row[k4*4+2]*ga.z + v_row[k4*4+3]*ga.w;
                u1 += v_row[k4*4+0]*gb.x + v_row[k4*4+1]*gb.y
                    + v_row[k4*4+2]*gb.z + v_row[k4*4+3]*gb.w;
            }
            *(float2*)(sU + j*8 + 2*q) = make_float2(u0, u1);

            float z0=0.f, z1=0.f, z2=0.f, z3=0.f;
            #pragma unroll
            for (int k4 = 0; k4 < 4; ++k4) {
                float4 a0 = *(const float4*)(sA + (4*q+0)*SD + k4*4);
                float4 a1 = *(const float4*)(sA + (4*q+1)*SD + k4*4);
                float4 a2 = *(const float4*)(sA + (4*q+2)*SD + k4*4);
                float4 a3 = *(const float4*)(sA + (4*q+3)*SD + k4*4);
                z0 += v_row[k4*4+0]*a0.x + v_row[k4*4+1]*a0.y
                    + v_row[k4*4+2]*a0.z + v_row[k4*4+3]*a0.w;
                z1 += v_row[k4*4+0]*a1.x + v_row[k4*4+1]*a1.y
                    + v_row[k4*4+2]*a1.z + v_row[k4*4+3]*a1.w;
                z2 += v_row[k4*4+0]*a2.x + v_row[k4*4+1]*a2.y
                    + v_row[k4*4+2]*a2.z + v_row[k4*4+3]*a2.w;
                z3 += v_row[k4*4+0]*a3.x + v_row[k4*4+1]*a3.y
                    + v_row[k4*4+2]*a3.z + v_row[k4*4+3]*a3.w;
            }
            *(float4*)(sZ + j*SD + q*4) = make_float4(z0,z1,z2,z3);
            WFENCE();

            s = sy0;
            #pragma unroll
            for (int k = 0; k < 16; ++k) s += g_row[k]*sU[k*8 + n8];

            float ph0 = wj0, ph1 = wj1;
            #pragma unroll
            for (int k = 0; k < 16; ++k) {
                float2 uv = *(const float2*)(sU + k*8 + 2*q);
                ph0 += a_row[k]*uv.x;
                ph1 += a_row[k]*uv.y;
            }
            *(float2*)(sPH + j*SPH + 2*q) = make_float2(ph0, ph1);

            float p0=0.f, p1=0.f, p2=0.f, p3=0.f;
            #pragma unroll
            for (int k = 0; k < 16; ++k) {
                float4 zv = *(const float4*)(sZ + k*SD + q*4);
                p0 += a_row[k]*zv.x; p1 += a_row[k]*zv.y;
                p2 += a_row[k]*zv.z; p3 += a_row[k]*zv.w;
            }
            pr[0]=p0+sxr.x; pr[1]=p1+sxr.y; pr[2]=p2+sxr.z; pr[3]=p3+sxr.w;
            *(float4*)(sP + j*SD + q*4) = make_float4(pr[0],pr[1],pr[2],pr[3]);
        }
        WFENCE();

        out[OFF_VY + (size_t)t*64 + l] = s;

        {
            float cp1 = 0.f, cp2 = 0.f;
            #pragma unroll
            for (int i = 0; i < 16; ++i) {
                cp1 += c_row[i]*sP[i*SD + n8];
                cp2 += c_row[i]*sP[i*SD + n8 + 8];
            }
            sCP[m8*SD + n8]     = cp1;
            sCP[m8*SD + n8 + 8] = cp2;
        }

        float sv  = s;
        float ld2 = 0.f;
        #pragma unroll
        for (int p = 0; p < 8; ++p) {
            float app = __shfl(sv, p*9, 64);
            float apn = __shfl(sv, p*8 + n8, 64);
            float amp = __shfl(sv, m8*8 + p, 64);
            float d   = __builtin_amdgcn_rcpf(app);
            d = d * (2.0f - app*d);
            ld2 += __log2f(app);
            float rps  = apn * d;
            float vtop = (n8 == p) ? d          : rps;
            float voth = (n8 == p) ? (-amp * d) : fmaf(-amp, rps, sv);
            sv = (m8 == p) ? vtop : voth;
        }
        acc_ld2 += ld2;

        sSinv[l] = sv;
        ws[t*WS_KSTRIDE + 128 + l] = sv;
        WFENCE();

        float phj[8];
        {
            float4 a0 = *(const float4*)(sPH + j*SPH + 0);
            float4 a1 = *(const float4*)(sPH + j*SPH + 4);
            phj[0]=a0.x; phj[1]=a0.y; phj[2]=a0.z; phj[3]=a0.w;
            phj[4]=a1.x; phj[5]=a1.y; phj[6]=a1.z; phj[7]=a1.w;
        }
        float kk[8] = {0.f,0.f,0.f,0.f,0.f,0.f,0.f,0.f};
        #pragma unroll
        for (int k = 0; k < 8; ++k) {
            float4 s0 = *(const float4*)(sSinv + k*8 + 0);
            float4 s1 = *(const float4*)(sSinv + k*8 + 4);
            kk[0]+=phj[k]*s0.x; kk[1]+=phj[k]*s0.y; kk[2]+=phj[k]*s0.z; kk[3]+=phj[k]*s0.w;
            kk[4]+=phj[k]*s1.x; kk[5]+=phj[k]*s1.y; kk[6]+=phj[k]*s1.z; kk[7]+=phj[k]*s1.w;
        }
        float2 kpair = make_float2(kk[2*q], kk[2*q+1]);
        *(float2*)(ws + t*WS_KSTRIDE + j*8 + 2*q) = kpair;

        float vn0=pr[0], vn1=pr[1], vn2=pr[2], vn3=pr[3];
        #pragma unroll
        for (int m = 0; m < 8; ++m) {
            float4 cv = *(const float4*)(sCP + m*SD + q*4);
            vn0 -= kk[m]*cv.x; vn1 -= kk[m]*cv.y;
            vn2 -= kk[m]*cv.z; vn3 -= kk[m]*cv.w;
        }
        float4 vnq = make_float4(vn0,vn1,vn2,vn3);
        *(float4*)(sV + j*SD + q*4) = vnq;
        *(float4*)(out + OFF_V + ((size_t)t*256 + j*16 + q*4)) = vnq;

        float dmax = 1e9f;
        if (t > 0) {
            float d0 = fabsf(vn0 - v_row[4*q+0]);
            float d1 = fabsf(vn1 - v_row[4*q+1]);
            float d2 = fabsf(vn2 - v_row[4*q+2]);
            float d3 = fabsf(vn3 - v_row[4*q+3]);
            dmax = fmaxf(fmaxf(d0,d1), fmaxf(d2,d3));
        }
        convcnt = __all(dmax <= CONV_EPS) ? (convcnt + 1) : 0;

        if (convcnt >= 2 && t < NT-1) {
            tconv = t;
            acc_ld2 += (float)(NT-1 - t) * ld2;
            #pragma unroll 4
            for (int t2 = t+1; t2 < NT; ++t2) {
                out[OFF_VY + (size_t)t2*64 + l] = s;
                *(float4*)(out + OFF_V + ((size_t)t2*256 + j*16 + q*4)) = vnq;
                *(float2*)(ws + t2*WS_KSTRIDE + j*8 + 2*q) = kpair;
                ws[t2*WS_KSTRIDE + 128 + l] = sv;
            }
            break;
        }
        WFENCE();
    }

    if (l == 0) {
        ws[WS_LD2]   = acc_ld2;
        ws[WS_TCONV] = __int_as_float(tconv);
    }
}

// --- Phase 2a: fillBuffer-shaped broadcast. Batch-invariance holds for ALL t,
// --- and grid span ≡ 0 (mod region period) makes each thread's period offset
// --- loop-invariant: one load, then pure nt stores advancing one contiguous
// --- multi-MB front (exactly the pattern fillBuffer sustains 6.9 TB/s with).
__launch_bounds__(256)
__global__ void copy_kernel(float* __restrict__ out)
{
    const int tid = threadIdx.x;
    if (blockIdx.x < 1024) {
        // v region: period 16384 float4/batch; G = 262144 = 16*16384
        const size_t G = (size_t)1024 * 256;
        const size_t g = (size_t)blockIdx.x * 256 + tid;
        const nfloat4* src = (const nfloat4*)(out + OFF_V);
        nfloat4* dst = (nfloat4*)(out + OFF_V) + 16384;          // batch 1
        const size_t N4 = (size_t)(NB-1) * 16384;
        const nfloat4 val = src[g & 16383];
        #pragma unroll 4
        for (size_t i = g; i < N4; i += G)
            __builtin_nontemporal_store(val, dst + i);
    } else {
        // vy region: period 4096 float4/batch; G = 16384 = 4*4096
        const size_t G = (size_t)64 * 256;
        const size_t g = (size_t)(blockIdx.x - 1024) * 256 + tid;
        const nfloat4* src = (const nfloat4*)(out + OFF_VY);
        nfloat4* dst = (nfloat4*)(out + OFF_VY) + 4096;          // batch 1
        const size_t N4 = (size_t)(NB-1) * 4096;
        const nfloat4 val = src[g & 4095];
        #pragma unroll 4
        for (size_t i = g; i < N4; i += G)
            __builtin_nontemporal_store(val, dst + i);
    }
}

// ------- Phase 2b: per-batch mu recursion (register state, 2-deep prefetch)
__launch_bounds__(64)
__global__ void mu_kernel(const float* __restrict__ gy, const float* __restrict__ gu,
                          const float* __restrict__ gmu0, const float* __restrict__ gA,
                          const float* __restrict__ gBm, const float* __restrict__ gC,
                          float* __restrict__ ws, float* __restrict__ out)
{
    const int l  = threadIdx.x;
    const int b  = blockIdx.x;
    const int j  = l & 15;
    const int m8 = l >> 3;
    const int n8 = l & 7;

    float a_row[16];
    #pragma unroll
    for (int k4 = 0; k4 < 4; ++k4) {
        float4 t4 = *(const float4*)(gA + j*16 + k4*4);
        a_row[k4*4+0]=t4.x; a_row[k4*4+1]=t4.y; a_row[k4*4+2]=t4.z; a_row[k4*4+3]=t4.w;
    }
    float cn_row[16];
    #pragma unroll
    for (int k4 = 0; k4 < 4; ++k4) {
        float4 cv = *(const float4*)(gC + n8*16 + k4*4);
        cn_row[k4*4+0]=cv.x; cn_row[k4*4+1]=cv.y; cn_row[k4*4+2]=cv.z; cn_row[k4*4+3]=cv.w;
    }
    float gn_row[16];
    #pragma unroll
    for (int k4 = 0; k4 < 4; ++k4) {
        float4 gv = *(const float4*)(ws + WS_G + n8*16 + k4*4);
        gn_row[k4*4+0]=gv.x; gn_row[k4*4+1]=gv.y; gn_row[k4*4+2]=gv.z; gn_row[k4*4+3]=gv.w;
    }
    float4 cb    = *(const float4*)(ws + WS_CB + n8*4);
    float4 b_row = *(const float4*)(gBm + j*4);

    float muj = gmu0[b*16 + j];
    float part_acc = 0.f;

    float4 kA0 = *(const float4*)(ws + 0*WS_KSTRIDE + j*8);
    float4 kB0 = *(const float4*)(ws + 0*WS_KSTRIDE + j*8 + 4);
    float  sc0 = ws[0*WS_KSTRIDE + 128 + l];
    float  yy0 = gy[((size_t)b*NT)*8 + n8];
    float4 uu0 = *(const float4*)(gu + ((size_t)b*NT)*4);
    float4 kA1 = *(const float4*)(ws + 1*WS_KSTRIDE + j*8);
    float4 kB1 = *(const float4*)(ws + 1*WS_KSTRIDE + j*8 + 4);
    float  sc1 = ws[1*WS_KSTRIDE + 128 + l];
    float  yy1 = gy[((size_t)b*NT + 1)*8 + n8];
    float4 uu1 = *(const float4*)(gu + ((size_t)b*NT + 1)*4);

    #pragma unroll 1
    for (int t = 0; t < NT; ++t) {
        const int t2 = (t+2 < NT) ? (t+2) : (NT-1);
        float4 kA2 = *(const float4*)(ws + t2*WS_KSTRIDE + j*8);
        float4 kB2 = *(const float4*)(ws + t2*WS_KSTRIDE + j*8 + 4);
        float  sc2 = ws[t2*WS_KSTRIDE + 128 + l];
        float  yy2 = gy[((size_t)b*NT + t2)*8 + n8];
        float4 uu2 = *(const float4*)(gu + ((size_t)b*NT + t2)*4);

        float mub[16];
        #pragma unroll
        for (int k = 0; k < 16; ++k) mub[k] = lane_bcast(muj, k);

        float x_j, yp;
        if (t == 0) {
            x_j = muj;
            float yp0 = 0.f, yp1 = 0.f;
            #pragma unroll
            for (int k = 0; k < 16; k += 2) {
                yp0 += cn_row[k]*mub[k];
                yp1 += cn_row[k+1]*mub[k+1];
            }
            yp = yp0 + yp1;
        } else {
            float x0 = b_row.x*uu0.x + b_row.y*uu0.y;
            float x1 = b_row.z*uu0.z + b_row.w*uu0.w;
            float y0 = cb.x*uu0.x + cb.y*uu0.y;
            float y1 = cb.z*uu0.z + cb.w*uu0.w;
            #pragma unroll
            for (int k = 0; k < 16; k += 2) {
                x0 += a_row[k]*mub[k];    x1 += a_row[k+1]*mub[k+1];
                y0 += gn_row[k]*mub[k];   y1 += gn_row[k+1]*mub[k+1];
            }
            x_j = x0 + x1;
            yp  = y0 + y1;
        }
        float dn = yy0 - yp;
        if (l < 8) ntstore1(out + OFF_Y + ((size_t)b*NT + t)*8 + l, yp);

        float dl[8];
        #pragma unroll
        for (int m = 0; m < 8; ++m) dl[m] = lane_bcast(dn, m);
        float dm = __shfl(dn, m8, 64);

        float kk[8];
        kk[0]=kA0.x; kk[1]=kA0.y; kk[2]=kA0.z; kk[3]=kA0.w;
        kk[4]=kB0.x; kk[5]=kB0.y; kk[6]=kB0.z; kk[7]=kB0.w;

        float mu_new = x_j;
        #pragma unroll
        for (int m = 0; m < 8; ++m) mu_new += kk[m]*dl[m];
        muj = mu_new;
        if (l < 16) ntstore1(out + OFF_MU + ((size_t)b*NT + t)*16 + j, muj);

        part_acc += sc0 * dm * dn;

        kA0 = kA1; kB0 = kB1; sc0 = sc1; yy0 = yy1; uu0 = uu1;
        kA1 = kA2; kB1 = kB2; sc1 = sc2; yy1 = yy2; uu1 = uu2;
    }

    #pragma unroll
    for (int mask = 32; mask >= 1; mask >>= 1)
        part_acc += __shfl_xor(part_acc, mask, 64);
    if (l == 0) ws[WS_SSQ + b] = part_acc;
}

// ---------------- Phase 3: logp reduction -----------------
__launch_bounds__(256)
__global__ void logp_sum(const float* __restrict__ ws, float* __restrict__ out)
{
    __shared__ float red[256];
    int t = threadIdx.x;
    float sv = 0.f;
    #pragma unroll
    for (int k = 0; k < 8; ++k) sv += ws[WS_SSQ + t + 256*k];
    red[t] = sv;
    __syncthreads();
    #pragma unroll 1
    for (int off = 128; off >= 1; off >>= 1) {
        if (t < off) red[t] += red[t + off];
        __syncthreads();
    }
    if (t == 0) {
        float ld2sum = ws[WS_LD2];
        out[OFF_LOGP] = -0.5f*(14.703016531274762f
                               + 0.6931471805599453f*ld2sum*(1.0f/256.0f)
                               + red[0]*(1.0f/524288.0f));
    }
}

extern "C" void kernel_launch(void* const* d_in, const int* in_sizes, int n_in,
                              void* d_out, int out_size, void* d_ws, size_t ws_size,
                              hipStream_t stream) {
    (void)in_sizes; (void)n_in; (void)out_size; (void)ws_size;
    const float* gy   = (const float*)d_in[0];
    const float* gu   = (const float*)d_in[1];
    const float* gmu0 = (const float*)d_in[2];
    const float* gP0  = (const float*)d_in[3];
    const float* gA   = (const float*)d_in[4];
    const float* gBm  = (const float*)d_in[5];
    const float* gC   = (const float*)d_in[6];
    const float* gSx  = (const float*)d_in[7];
    const float* gSy  = (const float*)d_in[8];
    float* out = (float*)d_out;
    float* ws  = (float*)d_ws;

    hipLaunchKernelGGL(cov_kernel, dim3(1), dim3(64), 0, stream,
                       gP0, gA, gBm, gC, gSx, gSy, out, ws);
    hipLaunchKernelGGL(copy_kernel, dim3(1024 + 64), dim3(256), 0, stream, out);
    hipLaunchKernelGGL(mu_kernel, dim3(NB), dim3(64), 0, stream,
                       gy, gu, gmu0, gA, gBm, gC, ws, out);
    hipLaunchKernelGGL(logp_sum, dim3(1), dim3(256), 0, stream, ws, out);
}

// Round 18
// 282.904 us; speedup vs baseline: 1.1677x; 1.1677x over previous
//
#include <hip/hip_runtime.h>
#include <cstddef>

#define NB 2048
#define NT 256

#define SD  20
#define SPH 12
#define SG  20

#define WS_KSTRIDE 192
#define WS_LD2     49152
#define WS_SSQ     49168
#define WS_G       51216
#define WS_CB      51344
#define WS_TCONV   51376

#define CONV_EPS 1e-4f

#define WFENCE() __builtin_amdgcn_wave_barrier()

#define OFF_MU 0
#define OFF_V  8388608
#define OFF_LOGP 142606336
#define OFF_Y  142606337
#define OFF_VY 146800641

__device__ __forceinline__ float lane_bcast(float v, int k) {
    return __int_as_float(__builtin_amdgcn_readlane(__float_as_int(v), k));
}

// native vector type for nontemporal builtins (HIP float4 is a class type)
typedef float nfloat4 __attribute__((ext_vector_type(4)));

__device__ __forceinline__ void ntstore4(float* p, float4 v) {
    nfloat4 nv; nv.x = v.x; nv.y = v.y; nv.z = v.z; nv.w = v.w;
    __builtin_nontemporal_store(nv, (nfloat4*)p);
}
__device__ __forceinline__ void ntstore1(float* p, float v) {
    __builtin_nontemporal_store(v, p);
}

// ---------------- Phase 1: batch-invariant Riccati recursion (1 block) -----
__launch_bounds__(64)
__global__ void cov_kernel(const float* __restrict__ gP0, const float* __restrict__ gA,
                           const float* __restrict__ gBm, const float* __restrict__ gC,
                           const float* __restrict__ gSx, const float* __restrict__ gSy,
                           float* __restrict__ out, float* __restrict__ ws)
{
    const int l  = threadIdx.x;
    const int j  = l & 15;
    const int q  = l >> 4;
    const int m8 = l >> 3;
    const int n8 = l & 7;

    __shared__ __align__(16) float sA[16*SD];
    __shared__ __align__(16) float sC[128];
    __shared__ __align__(16) float sG[8*SG];
    __shared__ __align__(16) float sW[16*8];
    __shared__ __align__(16) float sV[16*SD];
    __shared__ __align__(16) float sZ[16*SD];
    __shared__ __align__(16) float sP[16*SD];
    __shared__ __align__(16) float sCP[8*SD];
    __shared__ __align__(16) float sU[16*8];
    __shared__ __align__(16) float sPH[16*SPH];
    __shared__ __align__(16) float sSinv[64];

    {
        int r = l >> 2, c4 = l & 3;
        *(float4*)(sA + r*SD + c4*4) = *(const float4*)(gA + r*16 + c4*4);
        if (l < 32) *(float4*)(sC + l*4) = *(const float4*)(gC + l*4);
    }

    float a_row[16];
    #pragma unroll
    for (int k4 = 0; k4 < 4; ++k4) {
        float4 t4 = *(const float4*)(gA + j*16 + k4*4);
        a_row[k4*4+0]=t4.x; a_row[k4*4+1]=t4.y; a_row[k4*4+2]=t4.z; a_row[k4*4+3]=t4.w;
    }
    float4 sxr = *(const float4*)(gSx + j*16 + q*4);
    float  syr = gSy[l];

    WFENCE();

    float c_row[16];
    #pragma unroll
    for (int k4 = 0; k4 < 4; ++k4) {
        float4 cv = *(const float4*)(sC + m8*16 + k4*4);
        c_row[k4*4+0]=cv.x; c_row[k4*4+1]=cv.y; c_row[k4*4+2]=cv.z; c_row[k4*4+3]=cv.w;
    }

    {
        float g1 = 0.f, g2 = 0.f;
        #pragma unroll
        for (int i = 0; i < 16; ++i) {
            g1 += c_row[i]*sA[i*SD + n8];
            g2 += c_row[i]*sA[i*SD + n8 + 8];
        }
        sG[m8*SG + n8]     = g1;
        sG[m8*SG + n8 + 8] = g2;
        ws[WS_G + m8*16 + n8]     = g1;
        ws[WS_G + m8*16 + n8 + 8] = g2;

        if (l < 32) {
            int m = l >> 2, c = l & 3;
            float acc = 0.f;
            #pragma unroll
            for (int i = 0; i < 16; ++i) acc += sC[m*16 + i] * gBm[i*4 + c];
            ws[WS_CB + m*4 + c] = acc;
        }

        float qrow[16];
        #pragma unroll
        for (int k4 = 0; k4 < 4; ++k4) {
            float4 qv = *(const float4*)(gSx + j*16 + k4*4);
            qrow[k4*4+0]=qv.x; qrow[k4*4+1]=qv.y; qrow[k4*4+2]=qv.z; qrow[k4*4+3]=qv.w;
        }
        float w0 = 0.f, w1 = 0.f;
        #pragma unroll
        for (int k = 0; k < 16; ++k) {
            w0 += qrow[k]*sC[(2*q)*16 + k];
            w1 += qrow[k]*sC[(2*q+1)*16 + k];
        }
        sW[j*8 + 2*q]     = w0;
        sW[j*8 + 2*q + 1] = w1;
    }
    WFENCE();

    float sy0 = syr;
    #pragma unroll
    for (int k = 0; k < 16; ++k) sy0 += c_row[k]*sW[k*8 + n8];

    float g_row[16];
    #pragma unroll
    for (int k4 = 0; k4 < 4; ++k4) {
        float4 gv = *(const float4*)(sG + m8*SG + k4*4);
        g_row[k4*4+0]=gv.x; g_row[k4*4+1]=gv.y; g_row[k4*4+2]=gv.z; g_row[k4*4+3]=gv.w;
    }
    float wj0 = sW[j*8 + 2*q], wj1 = sW[j*8 + 2*q + 1];

    float acc_ld2 = 0.f;
    float pr[4];
    int   convcnt = 0;
    int   tconv   = NT-1;

    #pragma unroll 1
    for (int t = 0; t < NT; ++t) {
        float s;
        float v_row[16];

        if (t == 0) {
            float4 p0 = *(const float4*)(gP0 + j*16 + q*4);
            pr[0]=p0.x; pr[1]=p0.y; pr[2]=p0.z; pr[3]=p0.w;
            *(float4*)(sP + j*SD + q*4) = p0;
            WFENCE();
            float p_row[16];
            #pragma unroll
            for (int k4 = 0; k4 < 4; ++k4) {
                float4 pv = *(const float4*)(sP + j*SD + k4*4);
                p_row[k4*4+0]=pv.x; p_row[k4*4+1]=pv.y; p_row[k4*4+2]=pv.z; p_row[k4*4+3]=pv.w;
            }
            float ph0=0.f, ph1=0.f;
            #pragma unroll
            for (int k = 0; k < 16; ++k) {
                ph0 += p_row[k]*sC[(2*q)*16 + k];
                ph1 += p_row[k]*sC[(2*q+1)*16 + k];
            }
            *(float2*)(sPH + j*SPH + 2*q) = make_float2(ph0, ph1);
            WFENCE();
            s = syr;
            #pragma unroll
            for (int k = 0; k < 16; ++k) s += c_row[k]*sPH[k*SPH + n8];
        } else {
            #pragma unroll
            for (int k4 = 0; k4 < 4; ++k4) {
                float4 vv = *(const float4*)(sV + j*SD + k4*4);
                v_row[k4*4+0]=vv.x; v_row[k4*4+1]=vv.y; v_row[k4*4+2]=vv.z; v_row[k4*4+3]=vv.w;
            }
            float u0 = 0.f, u1 = 0.f;
            #pragma unroll
            for (int k4 = 0; k4 < 4; ++k4) {
                float4 ga = *(const float4*)(sG + (2*q)*SG + k4*4);
                float4 gb = *(const float4*)(sG + (2*q+1)*SG + k4*4);
                u0 += v_row[k4*4+0]*ga.x + v_row[k4*4+1]*ga.y
                    + v_row[k4*4+2]*ga.z + v_row[k4*4+3]*ga.w;
                u1 += v_row[k4*4+0]*gb.x + v_row[k4*4+1]*gb.y
                    + v_row[k4*4+2]*gb.z + v_row[k4*4+3]*gb.w;
            }
            *(float2*)(sU + j*8 + 2*q) = make_float2(u0, u1);

            float z0=0.f, z1=0.f, z2=0.f, z3=0.f;
            #pragma unroll
            for (int k4 = 0; k4 < 4; ++k4) {
                float4 a0 = *(const float4*)(sA + (4*q+0)*SD + k4*4);
                float4 a1 = *(const float4*)(sA + (4*q+1)*SD + k4*4);
                float4 a2 = *(const float4*)(sA + (4*q+2)*SD + k4*4);
                float4 a3 = *(const float4*)(sA + (4*q+3)*SD + k4*4);
                z0 += v_row[k4*4+0]*a0.x + v_row[k4*4+1]*a0.y
                    + v_row[k4*4+2]*a0.z + v_row[k4*4+3]*a0.w;
                z1 += v_row[k4*4+0]*a1.x + v_row[k4*4+1]*a1.y
                    + v_row[k4*4+2]*a1.z + v_row[k4*4+3]*a1.w;
                z2 += v_row[k4*4+0]*a2.x + v_row[k4*4+1]*a2.y
                    + v_row[k4*4+2]*a2.z + v_row[k4*4+3]*a2.w;
                z3 += v_row[k4*4+0]*a3.x + v_row[k4*4+1]*a3.y
                    + v_row[k4*4+2]*a3.z + v_row[k4*4+3]*a3.w;
            }
            *(float4*)(sZ + j*SD + q*4) = make_float4(z0,z1,z2,z3);
            WFENCE();

            s = sy0;
            #pragma unroll
            for (int k = 0; k < 16; ++k) s += g_row[k]*sU[k*8 + n8];

            float ph0 = wj0, ph1 = wj1;
            #pragma unroll
            for (int k = 0; k < 16; ++k) {
                float2 uv = *(const float2*)(sU + k*8 + 2*q);
                ph0 += a_row[k]*uv.x;
                ph1 += a_row[k]*uv.y;
            }
            *(float2*)(sPH + j*SPH + 2*q) = make_float2(ph0, ph1);

            float p0=0.f, p1=0.f, p2=0.f, p3=0.f;
            #pragma unroll
            for (int k = 0; k < 16; ++k) {
                float4 zv = *(const float4*)(sZ + k*SD + q*4);
                p0 += a_row[k]*zv.x; p1 += a_row[k]*zv.y;
                p2 += a_row[k]*zv.z; p3 += a_row[k]*zv.w;
            }
            pr[0]=p0+sxr.x; pr[1]=p1+sxr.y; pr[2]=p2+sxr.z; pr[3]=p3+sxr.w;
            *(float4*)(sP + j*SD + q*4) = make_float4(pr[0],pr[1],pr[2],pr[3]);
        }
        WFENCE();

        out[OFF_VY + (size_t)t*64 + l] = s;

        {
            float cp1 = 0.f, cp2 = 0.f;
            #pragma unroll
            for (int i = 0; i < 16; ++i) {
                cp1 += c_row[i]*sP[i*SD + n8];
                cp2 += c_row[i]*sP[i*SD + n8 + 8];
            }
            sCP[m8*SD + n8]     = cp1;
            sCP[m8*SD + n8 + 8] = cp2;
        }

        float sv  = s;
        float ld2 = 0.f;
        #pragma unroll
        for (int p = 0; p < 8; ++p) {
            float app = __shfl(sv, p*9, 64);
            float apn = __shfl(sv, p*8 + n8, 64);
            float amp = __shfl(sv, m8*8 + p, 64);
            float d   = __builtin_amdgcn_rcpf(app);
            d = d * (2.0f - app*d);
            ld2 += __log2f(app);
            float rps  = apn * d;
            float vtop = (n8 == p) ? d          : rps;
            float voth = (n8 == p) ? (-amp * d) : fmaf(-amp, rps, sv);
            sv = (m8 == p) ? vtop : voth;
        }
        acc_ld2 += ld2;

        sSinv[l] = sv;
        ws[t*WS_KSTRIDE + 128 + l] = sv;
        WFENCE();

        float phj[8];
        {
            float4 a0 = *(const float4*)(sPH + j*SPH + 0);
            float4 a1 = *(const float4*)(sPH + j*SPH + 4);
            phj[0]=a0.x; phj[1]=a0.y; phj[2]=a0.z; phj[3]=a0.w;
            phj[4]=a1.x; phj[5]=a1.y; phj[6]=a1.z; phj[7]=a1.w;
        }
        float kk[8] = {0.f,0.f,0.f,0.f,0.f,0.f,0.f,0.f};
        #pragma unroll
        for (int k = 0; k < 8; ++k) {
            float4 s0 = *(const float4*)(sSinv + k*8 + 0);
            float4 s1 = *(const float4*)(sSinv + k*8 + 4);
            kk[0]+=phj[k]*s0.x; kk[1]+=phj[k]*s0.y; kk[2]+=phj[k]*s0.z; kk[3]+=phj[k]*s0.w;
            kk[4]+=phj[k]*s1.x; kk[5]+=phj[k]*s1.y; kk[6]+=phj[k]*s1.z; kk[7]+=phj[k]*s1.w;
        }
        float2 kpair = make_float2(kk[2*q], kk[2*q+1]);
        *(float2*)(ws + t*WS_KSTRIDE + j*8 + 2*q) = kpair;

        float vn0=pr[0], vn1=pr[1], vn2=pr[2], vn3=pr[3];
        #pragma unroll
        for (int m = 0; m < 8; ++m) {
            float4 cv = *(const float4*)(sCP + m*SD + q*4);
            vn0 -= kk[m]*cv.x; vn1 -= kk[m]*cv.y;
            vn2 -= kk[m]*cv.z; vn3 -= kk[m]*cv.w;
        }
        float4 vnq = make_float4(vn0,vn1,vn2,vn3);
        *(float4*)(sV + j*SD + q*4) = vnq;
        *(float4*)(out + OFF_V + ((size_t)t*256 + j*16 + q*4)) = vnq;

        float dmax = 1e9f;
        if (t > 0) {
            float d0 = fabsf(vn0 - v_row[4*q+0]);
            float d1 = fabsf(vn1 - v_row[4*q+1]);
            float d2 = fabsf(vn2 - v_row[4*q+2]);
            float d3 = fabsf(vn3 - v_row[4*q+3]);
            dmax = fmaxf(fmaxf(d0,d1), fmaxf(d2,d3));
        }
        convcnt = __all(dmax <= CONV_EPS) ? (convcnt + 1) : 0;

        if (convcnt >= 2 && t < NT-1) {
            tconv = t;
            acc_ld2 += (float)(NT-1 - t) * ld2;
            #pragma unroll 4
            for (int t2 = t+1; t2 < NT; ++t2) {
                out[OFF_VY + (size_t)t2*64 + l] = s;
                *(float4*)(out + OFF_V + ((size_t)t2*256 + j*16 + q*4)) = vnq;
                *(float2*)(ws + t2*WS_KSTRIDE + j*8 + 2*q) = kpair;
                ws[t2*WS_KSTRIDE + 128 + l] = sv;
            }
            break;
        }
        WFENCE();
    }

    if (l == 0) {
        ws[WS_LD2]   = acc_ld2;
        ws[WS_TCONV] = __int_as_float(tconv);
    }
}

// mu-step phase: consume slot (KA,KB,SC,YY,UU) for step TT, then refill the
// slot for step TT+8 (8-deep software pipeline; all names static -> registers)
#define MU_PHASE(TT, KA, KB, SC, YY, UU)                                      \
    do {                                                                      \
        float mub[16];                                                        \
        _Pragma("unroll")                                                     \
        for (int k = 0; k < 16; ++k) mub[k] = lane_bcast(muj, k);             \
        float x_j, yp;                                                        \
        if ((TT) == 0) {                                                      \
            x_j = muj;                                                        \
            float yp0 = 0.f, yp1 = 0.f;                                       \
            _Pragma("unroll")                                                 \
            for (int k = 0; k < 16; k += 2) {                                 \
                yp0 += cn_row[k]*mub[k];                                      \
                yp1 += cn_row[k+1]*mub[k+1];                                  \
            }                                                                 \
            yp = yp0 + yp1;                                                   \
        } else {                                                              \
            float x0 = b_row.x*(UU).x + b_row.y*(UU).y;                       \
            float x1 = b_row.z*(UU).z + b_row.w*(UU).w;                       \
            float y0 = cb.x*(UU).x + cb.y*(UU).y;                             \
            float y1 = cb.z*(UU).z + cb.w*(UU).w;                             \
            _Pragma("unroll")                                                 \
            for (int k = 0; k < 16; k += 2) {                                 \
                x0 += a_row[k]*mub[k];    x1 += a_row[k+1]*mub[k+1];          \
                y0 += gn_row[k]*mub[k];   y1 += gn_row[k+1]*mub[k+1];         \
            }                                                                 \
            x_j = x0 + x1;                                                    \
            yp  = y0 + y1;                                                    \
        }                                                                     \
        float dn = (YY) - yp;                                                 \
        if (l < 8) ntstore1(out + OFF_Y + ((size_t)b*NT + (TT))*8 + l, yp);   \
        float dl[8];                                                          \
        _Pragma("unroll")                                                     \
        for (int m = 0; m < 8; ++m) dl[m] = lane_bcast(dn, m);                \
        float dm = __shfl(dn, m8, 64);                                        \
        float mu_new = x_j                                                    \
            + (KA).x*dl[0] + (KA).y*dl[1] + (KA).z*dl[2] + (KA).w*dl[3]       \
            + (KB).x*dl[4] + (KB).y*dl[5] + (KB).z*dl[6] + (KB).w*dl[7];      \
        muj = mu_new;                                                         \
        if (l < 16) ntstore1(out + OFF_MU + ((size_t)b*NT + (TT))*16 + j, muj); \
        part_acc += (SC) * dm * dn;                                           \
        {                                                                     \
            const int tp = ((TT)+8 < NT) ? (TT)+8 : NT-1;                     \
            (KA) = *(const float4*)(ws + tp*WS_KSTRIDE + j*8);                \
            (KB) = *(const float4*)(ws + tp*WS_KSTRIDE + j*8 + 4);            \
            (SC) = ws[tp*WS_KSTRIDE + 128 + l];                               \
            (YY) = gy[((size_t)b*NT + tp)*8 + n8];                            \
            (UU) = *(const float4*)(gu + ((size_t)b*NT + tp)*4);              \
        }                                                                     \
    } while (0)

// ------- Phase 2: role-split — mu (8-deep pipelined) ∥ copy blocks, nt stores
__launch_bounds__(64)
__global__ void stream_kernel(const float* __restrict__ gy, const float* __restrict__ gu,
                              const float* __restrict__ gmu0, const float* __restrict__ gA,
                              const float* __restrict__ gBm, const float* __restrict__ gC,
                              float* __restrict__ ws, float* __restrict__ out)
{
    const int l = threadIdx.x;

    if (blockIdx.x >= NB) {
        // ---- copy: per-batch contiguous walk-t; nt stores; v then vy ----
        const int b = blockIdx.x - NB;
        if (b == 0) return;                  // cov wrote batch 0
        const int tconv = __float_as_int(ws[WS_TCONV]);
        const int tc = (tconv < NT-1) ? tconv : (NT-1);
        const float* srcv = out + OFF_V;
        const float* srcy = out + OFF_VY;
        float* dstv = out + OFF_V  + (size_t)b*NT*256;
        float* dsty = out + OFF_VY + (size_t)b*NT*64;

        float4 vcur = make_float4(0.f,0.f,0.f,0.f);
        float  scur = 0.f;
        #pragma unroll 1
        for (int t = 0; t <= tc; ++t) {
            vcur = *(const float4*)(srcv + (size_t)t*256 + l*4);
            scur = srcy[(size_t)t*64 + l];
            ntstore4(dstv + (size_t)t*256 + l*4, vcur);
            ntstore1(dsty + (size_t)t*64 + l, scur);
        }
        int t = tc + 1;
        #pragma unroll 1
        for (; t + 3 < NT; t += 4) {
            ntstore4(dstv + (size_t)(t+0)*256 + l*4, vcur);
            ntstore4(dstv + (size_t)(t+1)*256 + l*4, vcur);
            ntstore4(dstv + (size_t)(t+2)*256 + l*4, vcur);
            ntstore4(dstv + (size_t)(t+3)*256 + l*4, vcur);
        }
        for (; t < NT; ++t) ntstore4(dstv + (size_t)t*256 + l*4, vcur);
        t = tc + 1;
        for (; t < NT && (t & 3); ++t) ntstore1(dsty + (size_t)t*64 + l, scur);
        {
            const int k4 = 4*(l & 15);
            float4 s4;
            s4.x = __shfl(scur, k4+0, 64);
            s4.y = __shfl(scur, k4+1, 64);
            s4.z = __shfl(scur, k4+2, 64);
            s4.w = __shfl(scur, k4+3, 64);
            #pragma unroll 1
            for (; t + 3 < NT; t += 4)
                ntstore4(dsty + (size_t)t*64 + 4*l, s4);
        }
        for (; t < NT; ++t) ntstore1(dsty + (size_t)t*64 + l, scur);
        return;
    }

    // ---- mu recursion: register state, 8-deep prefetch pipeline ----
    const int b  = blockIdx.x;
    const int j  = l & 15;
    const int m8 = l >> 3;
    const int n8 = l & 7;

    float a_row[16];
    #pragma unroll
    for (int k4 = 0; k4 < 4; ++k4) {
        float4 t4 = *(const float4*)(gA + j*16 + k4*4);
        a_row[k4*4+0]=t4.x; a_row[k4*4+1]=t4.y; a_row[k4*4+2]=t4.z; a_row[k4*4+3]=t4.w;
    }
    float cn_row[16];
    #pragma unroll
    for (int k4 = 0; k4 < 4; ++k4) {
        float4 cv = *(const float4*)(gC + n8*16 + k4*4);
        cn_row[k4*4+0]=cv.x; cn_row[k4*4+1]=cv.y; cn_row[k4*4+2]=cv.z; cn_row[k4*4+3]=cv.w;
    }
    float gn_row[16];
    #pragma unroll
    for (int k4 = 0; k4 < 4; ++k4) {
        float4 gv = *(const float4*)(ws + WS_G + n8*16 + k4*4);
        gn_row[k4*4+0]=gv.x; gn_row[k4*4+1]=gv.y; gn_row[k4*4+2]=gv.z; gn_row[k4*4+3]=gv.w;
    }
    float4 cb    = *(const float4*)(ws + WS_CB + n8*4);
    float4 b_row = *(const float4*)(gBm + j*4);

    float muj = gmu0[b*16 + j];
    float part_acc = 0.f;

    // 8 prefetch slots (named registers, never runtime-indexed)
    float4 kA0, kA1, kA2, kA3, kA4, kA5, kA6, kA7;
    float4 kB0, kB1, kB2, kB3, kB4, kB5, kB6, kB7;
    float  sc0, sc1, sc2, sc3, sc4, sc5, sc6, sc7;
    float  yy0, yy1, yy2, yy3, yy4, yy5, yy6, yy7;
    float4 uu0, uu1, uu2, uu3, uu4, uu5, uu6, uu7;

#define LOAD_SLOT(N)                                                          \
    kA##N = *(const float4*)(ws + (N)*WS_KSTRIDE + j*8);                      \
    kB##N = *(const float4*)(ws + (N)*WS_KSTRIDE + j*8 + 4);                  \
    sc##N = ws[(N)*WS_KSTRIDE + 128 + l];                                     \
    yy##N = gy[((size_t)b*NT + (N))*8 + n8];                                  \
    uu##N = *(const float4*)(gu + ((size_t)b*NT + (N))*4);
    LOAD_SLOT(0) LOAD_SLOT(1) LOAD_SLOT(2) LOAD_SLOT(3)
    LOAD_SLOT(4) LOAD_SLOT(5) LOAD_SLOT(6) LOAD_SLOT(7)
#undef LOAD_SLOT

    #pragma unroll 1
    for (int t = 0; t < NT; t += 8) {
        MU_PHASE(t+0, kA0, kB0, sc0, yy0, uu0);
        MU_PHASE(t+1, kA1, kB1, sc1, yy1, uu1);
        MU_PHASE(t+2, kA2, kB2, sc2, yy2, uu2);
        MU_PHASE(t+3, kA3, kB3, sc3, yy3, uu3);
        MU_PHASE(t+4, kA4, kB4, sc4, yy4, uu4);
        MU_PHASE(t+5, kA5, kB5, sc5, yy5, uu5);
        MU_PHASE(t+6, kA6, kB6, sc6, yy6, uu6);
        MU_PHASE(t+7, kA7, kB7, sc7, yy7, uu7);
    }

    #pragma unroll
    for (int mask = 32; mask >= 1; mask >>= 1)
        part_acc += __shfl_xor(part_acc, mask, 64);
    if (l == 0) ws[WS_SSQ + b] = part_acc;
}

// ---------------- Phase 3: logp reduction -----------------
__launch_bounds__(256)
__global__ void logp_sum(const float* __restrict__ ws, float* __restrict__ out)
{
    __shared__ float red[256];
    int t = threadIdx.x;
    float sv = 0.f;
    #pragma unroll
    for (int k = 0; k < 8; ++k) sv += ws[WS_SSQ + t + 256*k];
    red[t] = sv;
    __syncthreads();
    #pragma unroll 1
    for (int off = 128; off >= 1; off >>= 1) {
        if (t < off) red[t] += red[t + off];
        __syncthreads();
    }
    if (t == 0) {
        float ld2sum = ws[WS_LD2];
        out[OFF_LOGP] = -0.5f*(14.703016531274762f
                               + 0.6931471805599453f*ld2sum*(1.0f/256.0f)
                               + red[0]*(1.0f/524288.0f));
    }
}

extern "C" void kernel_launch(void* const* d_in, const int* in_sizes, int n_in,
                              void* d_out, int out_size, void* d_ws, size_t ws_size,
                              hipStream_t stream) {
    (void)in_sizes; (void)n_in; (void)out_size; (void)ws_size;
    const float* gy   = (const float*)d_in[0];
    const float* gu   = (const float*)d_in[1];
    const float* gmu0 = (const float*)d_in[2];
    const float* gP0  = (const float*)d_in[3];
    const float* gA   = (const float*)d_in[4];
    const float* gBm  = (const float*)d_in[5];
    const float* gC   = (const float*)d_in[6];
    const float* gSx  = (const float*)d_in[7];
    const float* gSy  = (const float*)d_in[8];
    float* out = (float*)d_out;
    float* ws  = (float*)d_ws;

    hipLaunchKernelGGL(cov_kernel, dim3(1), dim3(64), 0, stream,
                       gP0, gA, gBm, gC, gSx, gSy, out, ws);
    hipLaunchKernelGGL(stream_kernel, dim3(2*NB), dim3(64), 0, stream,
                       gy, gu, gmu0, gA, gBm, gC, ws, out);
    hipLaunchKernelGGL(logp_sum, dim3(1), dim3(256), 0, stream, ws, out);
}

// Round 19
// 263.842 us; speedup vs baseline: 1.2521x; 1.0723x over previous
//
#include <hip/hip_runtime.h>
#include <cstddef>

#define NB 2048
#define NT 256

#define SD  20
#define SPH 12
#define SG  20

#define WS_KSTRIDE 192
#define WS_LD2     49152
#define WS_SSQ     49168
#define WS_G       51216
#define WS_CB      51344
#define WS_TCONV   51376

#define CONV_EPS 3e-4f

#define WFENCE() __builtin_amdgcn_wave_barrier()

#define OFF_MU 0
#define OFF_V  8388608
#define OFF_LOGP 142606336
#define OFF_Y  142606337
#define OFF_VY 146800641

__device__ __forceinline__ float lane_bcast(float v, int k) {
    return __int_as_float(__builtin_amdgcn_readlane(__float_as_int(v), k));
}

// native vector type for nontemporal builtins (HIP float4 is a class type)
typedef float nfloat4 __attribute__((ext_vector_type(4)));

__device__ __forceinline__ void ntstore4(float* p, float4 v) {
    nfloat4 nv; nv.x = v.x; nv.y = v.y; nv.z = v.z; nv.w = v.w;
    __builtin_nontemporal_store(nv, (nfloat4*)p);
}
__device__ __forceinline__ void ntstore1(float* p, float v) {
    __builtin_nontemporal_store(v, p);
}

// ---------------- Phase 1: batch-invariant Riccati recursion (1 block) -----
__launch_bounds__(64)
__global__ void cov_kernel(const float* __restrict__ gP0, const float* __restrict__ gA,
                           const float* __restrict__ gBm, const float* __restrict__ gC,
                           const float* __restrict__ gSx, const float* __restrict__ gSy,
                           float* __restrict__ out, float* __restrict__ ws)
{
    const int l  = threadIdx.x;
    const int j  = l & 15;
    const int q  = l >> 4;
    const int m8 = l >> 3;
    const int n8 = l & 7;

    __shared__ __align__(16) float sA[16*SD];
    __shared__ __align__(16) float sC[128];
    __shared__ __align__(16) float sG[8*SG];
    __shared__ __align__(16) float sW[16*8];
    __shared__ __align__(16) float sV[16*SD];
    __shared__ __align__(16) float sZ[16*SD];
    __shared__ __align__(16) float sP[16*SD];
    __shared__ __align__(16) float sCP[8*SD];
    __shared__ __align__(16) float sU[16*8];
    __shared__ __align__(16) float sPH[16*SPH];
    __shared__ __align__(16) float sSinv[64];

    {
        int r = l >> 2, c4 = l & 3;
        *(float4*)(sA + r*SD + c4*4) = *(const float4*)(gA + r*16 + c4*4);
        if (l < 32) *(float4*)(sC + l*4) = *(const float4*)(gC + l*4);
    }

    float a_row[16];
    #pragma unroll
    for (int k4 = 0; k4 < 4; ++k4) {
        float4 t4 = *(const float4*)(gA + j*16 + k4*4);
        a_row[k4*4+0]=t4.x; a_row[k4*4+1]=t4.y; a_row[k4*4+2]=t4.z; a_row[k4*4+3]=t4.w;
    }
    float4 sxr = *(const float4*)(gSx + j*16 + q*4);
    float  syr = gSy[l];

    WFENCE();

    float c_row[16];
    #pragma unroll
    for (int k4 = 0; k4 < 4; ++k4) {
        float4 cv = *(const float4*)(sC + m8*16 + k4*4);
        c_row[k4*4+0]=cv.x; c_row[k4*4+1]=cv.y; c_row[k4*4+2]=cv.z; c_row[k4*4+3]=cv.w;
    }

    {
        float g1 = 0.f, g2 = 0.f;
        #pragma unroll
        for (int i = 0; i < 16; ++i) {
            g1 += c_row[i]*sA[i*SD + n8];
            g2 += c_row[i]*sA[i*SD + n8 + 8];
        }
        sG[m8*SG + n8]     = g1;
        sG[m8*SG + n8 + 8] = g2;
        ws[WS_G + m8*16 + n8]     = g1;
        ws[WS_G + m8*16 + n8 + 8] = g2;

        if (l < 32) {
            int m = l >> 2, c = l & 3;
            float acc = 0.f;
            #pragma unroll
            for (int i = 0; i < 16; ++i) acc += sC[m*16 + i] * gBm[i*4 + c];
            ws[WS_CB + m*4 + c] = acc;
        }

        float qrow[16];
        #pragma unroll
        for (int k4 = 0; k4 < 4; ++k4) {
            float4 qv = *(const float4*)(gSx + j*16 + k4*4);
            qrow[k4*4+0]=qv.x; qrow[k4*4+1]=qv.y; qrow[k4*4+2]=qv.z; qrow[k4*4+3]=qv.w;
        }
        float w0 = 0.f, w1 = 0.f;
        #pragma unroll
        for (int k = 0; k < 16; ++k) {
            w0 += qrow[k]*sC[(2*q)*16 + k];
            w1 += qrow[k]*sC[(2*q+1)*16 + k];
        }
        sW[j*8 + 2*q]     = w0;
        sW[j*8 + 2*q + 1] = w1;
    }
    WFENCE();

    float sy0 = syr;
    #pragma unroll
    for (int k = 0; k < 16; ++k) sy0 += c_row[k]*sW[k*8 + n8];

    float g_row[16];
    #pragma unroll
    for (int k4 = 0; k4 < 4; ++k4) {
        float4 gv = *(const float4*)(sG + m8*SG + k4*4);
        g_row[k4*4+0]=gv.x; g_row[k4*4+1]=gv.y; g_row[k4*4+2]=gv.z; g_row[k4*4+3]=gv.w;
    }
    float wj0 = sW[j*8 + 2*q], wj1 = sW[j*8 + 2*q + 1];

    float acc_ld2 = 0.f;
    float pr[4];
    int   tconv   = NT-1;

    #pragma unroll 1
    for (int t = 0; t < NT; ++t) {
        float s;
        float v_row[16];

        if (t == 0) {
            float4 p0 = *(const float4*)(gP0 + j*16 + q*4);
            pr[0]=p0.x; pr[1]=p0.y; pr[2]=p0.z; pr[3]=p0.w;
            *(float4*)(sP + j*SD + q*4) = p0;
            WFENCE();
            float p_row[16];
            #pragma unroll
            for (int k4 = 0; k4 < 4; ++k4) {
                float4 pv = *(const float4*)(sP + j*SD + k4*4);
                p_row[k4*4+0]=pv.x; p_row[k4*4+1]=pv.y; p_row[k4*4+2]=pv.z; p_row[k4*4+3]=pv.w;
            }
            float ph0=0.f, ph1=0.f;
            #pragma unroll
            for (int k = 0; k < 16; ++k) {
                ph0 += p_row[k]*sC[(2*q)*16 + k];
                ph1 += p_row[k]*sC[(2*q+1)*16 + k];
            }
            *(float2*)(sPH + j*SPH + 2*q) = make_float2(ph0, ph1);
            WFENCE();
            s = syr;
            #pragma unroll
            for (int k = 0; k < 16; ++k) s += c_row[k]*sPH[k*SPH + n8];
        } else {
            #pragma unroll
            for (int k4 = 0; k4 < 4; ++k4) {
                float4 vv = *(const float4*)(sV + j*SD + k4*4);
                v_row[k4*4+0]=vv.x; v_row[k4*4+1]=vv.y; v_row[k4*4+2]=vv.z; v_row[k4*4+3]=vv.w;
            }
            float u0 = 0.f, u1 = 0.f;
            #pragma unroll
            for (int k4 = 0; k4 < 4; ++k4) {
                float4 ga = *(const float4*)(sG + (2*q)*SG + k4*4);
                float4 gb = *(const float4*)(sG + (2*q+1)*SG + k4*4);
                u0 += v_row[k4*4+0]*ga.x + v_row[k4*4+1]*ga.y
                    + v_row[k4*4+2]*ga.z + v_row[k4*4+3]*ga.w;
                u1 += v_row[k4*4+0]*gb.x + v_row[k4*4+1]*gb.y
                    + v_row[k4*4+2]*gb.z + v_row[k4*4+3]*gb.w;
            }
            *(float2*)(sU + j*8 + 2*q) = make_float2(u0, u1);

            float z0=0.f, z1=0.f, z2=0.f, z3=0.f;
            #pragma unroll
            for (int k4 = 0; k4 < 4; ++k4) {
                float4 a0 = *(const float4*)(sA + (4*q+0)*SD + k4*4);
                float4 a1 = *(const float4*)(sA + (4*q+1)*SD + k4*4);
                float4 a2 = *(const float4*)(sA + (4*q+2)*SD + k4*4);
                float4 a3 = *(const float4*)(sA + (4*q+3)*SD + k4*4);
                z0 += v_row[k4*4+0]*a0.x + v_row[k4*4+1]*a0.y
                    + v_row[k4*4+2]*a0.z + v_row[k4*4+3]*a0.w;
                z1 += v_row[k4*4+0]*a1.x + v_row[k4*4+1]*a1.y
                    + v_row[k4*4+2]*a1.z + v_row[k4*4+3]*a1.w;
                z2 += v_row[k4*4+0]*a2.x + v_row[k4*4+1]*a2.y
                    + v_row[k4*4+2]*a2.z + v_row[k4*4+3]*a2.w;
                z3 += v_row[k4*4+0]*a3.x + v_row[k4*4+1]*a3.y
                    + v_row[k4*4+2]*a3.z + v_row[k4*4+3]*a3.w;
            }
            *(float4*)(sZ + j*SD + q*4) = make_float4(z0,z1,z2,z3);
            WFENCE();

            s = sy0;
            #pragma unroll
            for (int k = 0; k < 16; ++k) s += g_row[k]*sU[k*8 + n8];

            float ph0 = wj0, ph1 = wj1;
            #pragma unroll
            for (int k = 0; k < 16; ++k) {
                float2 uv = *(const float2*)(sU + k*8 + 2*q);
                ph0 += a_row[k]*uv.x;
                ph1 += a_row[k]*uv.y;
            }
            *(float2*)(sPH + j*SPH + 2*q) = make_float2(ph0, ph1);

            float p0=0.f, p1=0.f, p2=0.f, p3=0.f;
            #pragma unroll
            for (int k = 0; k < 16; ++k) {
                float4 zv = *(const float4*)(sZ + k*SD + q*4);
                p0 += a_row[k]*zv.x; p1 += a_row[k]*zv.y;
                p2 += a_row[k]*zv.z; p3 += a_row[k]*zv.w;
            }
            pr[0]=p0+sxr.x; pr[1]=p1+sxr.y; pr[2]=p2+sxr.z; pr[3]=p3+sxr.w;
            *(float4*)(sP + j*SD + q*4) = make_float4(pr[0],pr[1],pr[2],pr[3]);
        }
        WFENCE();

        out[OFF_VY + (size_t)t*64 + l] = s;

        {
            float cp1 = 0.f, cp2 = 0.f;
            #pragma unroll
            for (int i = 0; i < 16; ++i) {
                cp1 += c_row[i]*sP[i*SD + n8];
                cp2 += c_row[i]*sP[i*SD + n8 + 8];
            }
            sCP[m8*SD + n8]     = cp1;
            sCP[m8*SD + n8 + 8] = cp2;
        }

        float sv  = s;
        float ld2 = 0.f;
        #pragma unroll
        for (int p = 0; p < 8; ++p) {
            float app = __shfl(sv, p*9, 64);
            float apn = __shfl(sv, p*8 + n8, 64);
            float amp = __shfl(sv, m8*8 + p, 64);
            float d   = __builtin_amdgcn_rcpf(app);
            d = d * (2.0f - app*d);
            ld2 += __log2f(app);
            float rps  = apn * d;
            float vtop = (n8 == p) ? d          : rps;
            float voth = (n8 == p) ? (-amp * d) : fmaf(-amp, rps, sv);
            sv = (m8 == p) ? vtop : voth;
        }
        acc_ld2 += ld2;

        sSinv[l] = sv;
        ws[t*WS_KSTRIDE + 128 + l] = sv;
        WFENCE();

        float phj[8];
        {
            float4 a0 = *(const float4*)(sPH + j*SPH + 0);
            float4 a1 = *(const float4*)(sPH + j*SPH + 4);
            phj[0]=a0.x; phj[1]=a0.y; phj[2]=a0.z; phj[3]=a0.w;
            phj[4]=a1.x; phj[5]=a1.y; phj[6]=a1.z; phj[7]=a1.w;
        }
        float kk[8] = {0.f,0.f,0.f,0.f,0.f,0.f,0.f,0.f};
        #pragma unroll
        for (int k = 0; k < 8; ++k) {
            float4 s0 = *(const float4*)(sSinv + k*8 + 0);
            float4 s1 = *(const float4*)(sSinv + k*8 + 4);
            kk[0]+=phj[k]*s0.x; kk[1]+=phj[k]*s0.y; kk[2]+=phj[k]*s0.z; kk[3]+=phj[k]*s0.w;
            kk[4]+=phj[k]*s1.x; kk[5]+=phj[k]*s1.y; kk[6]+=phj[k]*s1.z; kk[7]+=phj[k]*s1.w;
        }
        float2 kpair = make_float2(kk[2*q], kk[2*q+1]);
        *(float2*)(ws + t*WS_KSTRIDE + j*8 + 2*q) = kpair;

        float vn0=pr[0], vn1=pr[1], vn2=pr[2], vn3=pr[3];
        #pragma unroll
        for (int m = 0; m < 8; ++m) {
            float4 cv = *(const float4*)(sCP + m*SD + q*4);
            vn0 -= kk[m]*cv.x; vn1 -= kk[m]*cv.y;
            vn2 -= kk[m]*cv.z; vn3 -= kk[m]*cv.w;
        }
        float4 vnq = make_float4(vn0,vn1,vn2,vn3);
        *(float4*)(sV + j*SD + q*4) = vnq;
        *(float4*)(out + OFF_V + ((size_t)t*256 + j*16 + q*4)) = vnq;

        float dmax = 1e9f;
        if (t > 0) {
            float d0 = fabsf(vn0 - v_row[4*q+0]);
            float d1 = fabsf(vn1 - v_row[4*q+1]);
            float d2 = fabsf(vn2 - v_row[4*q+2]);
            float d3 = fabsf(vn3 - v_row[4*q+3]);
            dmax = fmaxf(fmaxf(d0,d1), fmaxf(d2,d3));
        }

        // contraction => increments decrease monotonically; single test suffices
        if (__all(dmax <= CONV_EPS) && t < NT-1) {
            tconv = t;
            acc_ld2 += (float)(NT-1 - t) * ld2;
            #pragma unroll 4
            for (int t2 = t+1; t2 < NT; ++t2) {
                // b0 rows past tconv are never read again -> nt stores
                ntstore1(out + OFF_VY + (size_t)t2*64 + l, s);
                ntstore4(out + OFF_V + ((size_t)t2*256 + j*16 + q*4), vnq);
                *(float2*)(ws + t2*WS_KSTRIDE + j*8 + 2*q) = kpair;   // read by mu
                ws[t2*WS_KSTRIDE + 128 + l] = sv;                     // read by mu
            }
            break;
        }
        WFENCE();
    }

    if (l == 0) {
        ws[WS_LD2]   = acc_ld2;
        ws[WS_TCONV] = __int_as_float(tconv);
    }
}

// mu-step phase K (0..7, compile-time): consume slot, capture y into ybuf,
// refill slot for step TT+8; store y group every 8 steps (full-wave, coalesced)
#define MU_PHASE(TT, K, KA, KB, SC, YY, UU)                                   \
    do {                                                                      \
        float mub[16];                                                        \
        _Pragma("unroll")                                                     \
        for (int k = 0; k < 16; ++k) mub[k] = lane_bcast(muj, k);             \
        float x_j, yp;                                                        \
        if ((TT) == 0) {                                                      \
            x_j = muj;                                                        \
            float yp0 = 0.f, yp1 = 0.f;                                       \
            _Pragma("unroll")                                                 \
            for (int k = 0; k < 16; k += 2) {                                 \
                yp0 += cn_row[k]*mub[k];                                      \
                yp1 += cn_row[k+1]*mub[k+1];                                  \
            }                                                                 \
            yp = yp0 + yp1;                                                   \
        } else {                                                              \
            float x0 = b_row.x*(UU).x + b_row.y*(UU).y;                       \
            float x1 = b_row.z*(UU).z + b_row.w*(UU).w;                       \
            float y0 = cb.x*(UU).x + cb.y*(UU).y;                             \
            float y1 = cb.z*(UU).z + cb.w*(UU).w;                             \
            _Pragma("unroll")                                                 \
            for (int k = 0; k < 16; k += 2) {                                 \
                x0 += a_row[k]*mub[k];    x1 += a_row[k+1]*mub[k+1];          \
                y0 += gn_row[k]*mub[k];   y1 += gn_row[k+1]*mub[k+1];         \
            }                                                                 \
            x_j = x0 + x1;                                                    \
            yp  = y0 + y1;                                                    \
        }                                                                     \
        float dn = (YY) - yp;                                                 \
        ybuf = ((l >> 3) == (K)) ? yp : ybuf;   /* capture own t-row */       \
        float dl[8];                                                          \
        _Pragma("unroll")                                                     \
        for (int m = 0; m < 8; ++m) dl[m] = lane_bcast(dn, m);                \
        float dm = __shfl(dn, m8, 64);                                        \
        float mu_new = x_j                                                    \
            + (KA).x*dl[0] + (KA).y*dl[1] + (KA).z*dl[2] + (KA).w*dl[3]       \
            + (KB).x*dl[4] + (KB).y*dl[5] + (KB).z*dl[6] + (KB).w*dl[7];      \
        muj = mu_new;                                                         \
        if (l < 16) ntstore1(out + OFF_MU + ((size_t)b*NT + (TT))*16 + j, muj); \
        part_acc += (SC) * dm * dn;                                           \
        if ((K) == 7)                                                         \
            ntstore1(out + OFF_Y + ((size_t)b*NT + (TT) - 7)*8 + l, ybuf);    \
        {                                                                     \
            const int tp = ((TT)+8 < NT) ? (TT)+8 : NT-1;                     \
            (KA) = *(const float4*)(ws + tp*WS_KSTRIDE + j*8);                \
            (KB) = *(const float4*)(ws + tp*WS_KSTRIDE + j*8 + 4);            \
            (SC) = ws[tp*WS_KSTRIDE + 128 + l];                               \
            (YY) = gy[((size_t)b*NT + tp)*8 + n8];                            \
            (UU) = *(const float4*)(gu + ((size_t)b*NT + tp)*4);              \
        }                                                                     \
    } while (0)

// ------- Phase 2: role-split — mu (8-deep pipelined) ∥ copy blocks, nt stores
__launch_bounds__(64)
__global__ void stream_kernel(const float* __restrict__ gy, const float* __restrict__ gu,
                              const float* __restrict__ gmu0, const float* __restrict__ gA,
                              const float* __restrict__ gBm, const float* __restrict__ gC,
                              float* __restrict__ ws, float* __restrict__ out)
{
    const int l = threadIdx.x;

    if (blockIdx.x >= NB) {
        // ---- copy: per-batch contiguous walk-t; nt stores; v then vy ----
        const int b = blockIdx.x - NB;
        if (b == 0) return;                  // cov wrote batch 0
        const int tconv = __float_as_int(ws[WS_TCONV]);
        const int tc = (tconv < NT-1) ? tconv : (NT-1);
        const float* srcv = out + OFF_V;
        const float* srcy = out + OFF_VY;
        float* dstv = out + OFF_V  + (size_t)b*NT*256;
        float* dsty = out + OFF_VY + (size_t)b*NT*64;

        float4 vcur = make_float4(0.f,0.f,0.f,0.f);
        float  scur = 0.f;
        #pragma unroll 1
        for (int t = 0; t <= tc; ++t) {
            vcur = *(const float4*)(srcv + (size_t)t*256 + l*4);
            scur = srcy[(size_t)t*64 + l];
            ntstore4(dstv + (size_t)t*256 + l*4, vcur);
            ntstore1(dsty + (size_t)t*64 + l, scur);
        }
        int t = tc + 1;
        #pragma unroll 1
        for (; t + 3 < NT; t += 4) {
            ntstore4(dstv + (size_t)(t+0)*256 + l*4, vcur);
            ntstore4(dstv + (size_t)(t+1)*256 + l*4, vcur);
            ntstore4(dstv + (size_t)(t+2)*256 + l*4, vcur);
            ntstore4(dstv + (size_t)(t+3)*256 + l*4, vcur);
        }
        for (; t < NT; ++t) ntstore4(dstv + (size_t)t*256 + l*4, vcur);
        t = tc + 1;
        for (; t < NT && (t & 3); ++t) ntstore1(dsty + (size_t)t*64 + l, scur);
        {
            const int k4 = 4*(l & 15);
            float4 s4;
            s4.x = __shfl(scur, k4+0, 64);
            s4.y = __shfl(scur, k4+1, 64);
            s4.z = __shfl(scur, k4+2, 64);
            s4.w = __shfl(scur, k4+3, 64);
            #pragma unroll 1
            for (; t + 3 < NT; t += 4)
                ntstore4(dsty + (size_t)t*64 + 4*l, s4);
        }
        for (; t < NT; ++t) ntstore1(dsty + (size_t)t*64 + l, scur);
        return;
    }

    // ---- mu recursion: register state, 8-deep prefetch pipeline ----
    const int b  = blockIdx.x;
    const int j  = l & 15;
    const int m8 = l >> 3;
    const int n8 = l & 7;

    float a_row[16];
    #pragma unroll
    for (int k4 = 0; k4 < 4; ++k4) {
        float4 t4 = *(const float4*)(gA + j*16 + k4*4);
        a_row[k4*4+0]=t4.x; a_row[k4*4+1]=t4.y; a_row[k4*4+2]=t4.z; a_row[k4*4+3]=t4.w;
    }
    float cn_row[16];
    #pragma unroll
    for (int k4 = 0; k4 < 4; ++k4) {
        float4 cv = *(const float4*)(gC + n8*16 + k4*4);
        cn_row[k4*4+0]=cv.x; cn_row[k4*4+1]=cv.y; cn_row[k4*4+2]=cv.z; cn_row[k4*4+3]=cv.w;
    }
    float gn_row[16];
    #pragma unroll
    for (int k4 = 0; k4 < 4; ++k4) {
        float4 gv = *(const float4*)(ws + WS_G + n8*16 + k4*4);
        gn_row[k4*4+0]=gv.x; gn_row[k4*4+1]=gv.y; gn_row[k4*4+2]=gv.z; gn_row[k4*4+3]=gv.w;
    }
    float4 cb    = *(const float4*)(ws + WS_CB + n8*4);
    float4 b_row = *(const float4*)(gBm + j*4);

    float muj = gmu0[b*16 + j];
    float part_acc = 0.f;
    float ybuf = 0.f;

    // 8 prefetch slots (named registers, never runtime-indexed)
    float4 kA0, kA1, kA2, kA3, kA4, kA5, kA6, kA7;
    float4 kB0, kB1, kB2, kB3, kB4, kB5, kB6, kB7;
    float  sc0, sc1, sc2, sc3, sc4, sc5, sc6, sc7;
    float  yy0, yy1, yy2, yy3, yy4, yy5, yy6, yy7;
    float4 uu0, uu1, uu2, uu3, uu4, uu5, uu6, uu7;

#define LOAD_SLOT(N)                                                          \
    kA##N = *(const float4*)(ws + (N)*WS_KSTRIDE + j*8);                      \
    kB##N = *(const float4*)(ws + (N)*WS_KSTRIDE + j*8 + 4);                  \
    sc##N = ws[(N)*WS_KSTRIDE + 128 + l];                                     \
    yy##N = gy[((size_t)b*NT + (N))*8 + n8];                                  \
    uu##N = *(const float4*)(gu + ((size_t)b*NT + (N))*4);
    LOAD_SLOT(0) LOAD_SLOT(1) LOAD_SLOT(2) LOAD_SLOT(3)
    LOAD_SLOT(4) LOAD_SLOT(5) LOAD_SLOT(6) LOAD_SLOT(7)
#undef LOAD_SLOT

    #pragma unroll 1
    for (int t = 0; t < NT; t += 8) {
        MU_PHASE(t+0, 0, kA0, kB0, sc0, yy0, uu0);
        MU_PHASE(t+1, 1, kA1, kB1, sc1, yy1, uu1);
        MU_PHASE(t+2, 2, kA2, kB2, sc2, yy2, uu2);
        MU_PHASE(t+3, 3, kA3, kB3, sc3, yy3, uu3);
        MU_PHASE(t+4, 4, kA4, kB4, sc4, yy4, uu4);
        MU_PHASE(t+5, 5, kA5, kB5, sc5, yy5, uu5);
        MU_PHASE(t+6, 6, kA6, kB6, sc6, yy6, uu6);
        MU_PHASE(t+7, 7, kA7, kB7, sc7, yy7, uu7);
    }

    #pragma unroll
    for (int mask = 32; mask >= 1; mask >>= 1)
        part_acc += __shfl_xor(part_acc, mask, 64);
    if (l == 0) ws[WS_SSQ + b] = part_acc;
}

// ---------------- Phase 3: logp reduction -----------------
__launch_bounds__(256)
__global__ void logp_sum(const float* __restrict__ ws, float* __restrict__ out)
{
    __shared__ float red[256];
    int t = threadIdx.x;
    float sv = 0.f;
    #pragma unroll
    for (int k = 0; k < 8; ++k) sv += ws[WS_SSQ + t + 256*k];
    red[t] = sv;
    __syncthreads();
    #pragma unroll 1
    for (int off = 128; off >= 1; off >>= 1) {
        if (t < off) red[t] += red[t + off];
        __syncthreads();
    }
    if (t == 0) {
        float ld2sum = ws[WS_LD2];
        out[OFF_LOGP] = -0.5f*(14.703016531274762f
                               + 0.6931471805599453f*ld2sum*(1.0f/256.0f)
                               + red[0]*(1.0f/524288.0f));
    }
}

extern "C" void kernel_launch(void* const* d_in, const int* in_sizes, int n_in,
                              void* d_out, int out_size, void* d_ws, size_t ws_size,
                              hipStream_t stream) {
    (void)in_sizes; (void)n_in; (void)out_size; (void)ws_size;
    const float* gy   = (const float*)d_in[0];
    const float* gu   = (const float*)d_in[1];
    const float* gmu0 = (const float*)d_in[2];
    const float* gP0  = (const float*)d_in[3];
    const float* gA   = (const float*)d_in[4];
    const float* gBm  = (const float*)d_in[5];
    const float* gC   = (const float*)d_in[6];
    const float* gSx  = (const float*)d_in[7];
    const float* gSy  = (const float*)d_in[8];
    float* out = (float*)d_out;
    float* ws  = (float*)d_ws;

    hipLaunchKernelGGL(cov_kernel, dim3(1), dim3(64), 0, stream,
                       gP0, gA, gBm, gC, gSx, gSy, out, ws);
    hipLaunchKernelGGL(stream_kernel, dim3(2*NB), dim3(64), 0, stream,
                       gy, gu, gmu0, gA, gBm, gC, ws, out);
    hipLaunchKernelGGL(logp_sum, dim3(1), dim3(256), 0, stream, ws, out);
}

// Round 20
// 263.683 us; speedup vs baseline: 1.2528x; 1.0006x over previous
//
#include <hip/hip_runtime.h>
#include <cstddef>

#define NB 2048
#define NT 256

#define SD  20
#define SPH 12
#define SG  20

#define WS_KSTRIDE 192
#define WS_LD2     49152
#define WS_SSQ     49168
#define WS_G       51216
#define WS_CB      51344
#define WS_TCONV   51376

#define CONV_EPS 3e-4f

#define WFENCE() __builtin_amdgcn_wave_barrier()

#define OFF_MU 0
#define OFF_V  8388608
#define OFF_LOGP 142606336
#define OFF_Y  142606337
#define OFF_VY 146800641

// phase-2 role partition: 512 mu (4 waves = 4 batches each) + 448 v-copy
// (448*256 = 7*16384: period-aligned) + 64 vy-copy (64*256 = 4*4096)
#define MU_BLOCKS  512
#define VC_BLOCKS  448
#define VYC_BLOCKS 64

__device__ __forceinline__ float lane_bcast(float v, int k) {
    return __int_as_float(__builtin_amdgcn_readlane(__float_as_int(v), k));
}

typedef float nfloat4 __attribute__((ext_vector_type(4)));

__device__ __forceinline__ void ntstore4(float* p, float4 v) {
    nfloat4 nv; nv.x = v.x; nv.y = v.y; nv.z = v.z; nv.w = v.w;
    __builtin_nontemporal_store(nv, (nfloat4*)p);
}
__device__ __forceinline__ void ntstore1(float* p, float v) {
    __builtin_nontemporal_store(v, p);
}

// ---------------- Phase 1: batch-invariant Riccati recursion (1 block) -----
__launch_bounds__(64)
__global__ void cov_kernel(const float* __restrict__ gP0, const float* __restrict__ gA,
                           const float* __restrict__ gBm, const float* __restrict__ gC,
                           const float* __restrict__ gSx, const float* __restrict__ gSy,
                           float* __restrict__ out, float* __restrict__ ws)
{
    const int l  = threadIdx.x;
    const int j  = l & 15;
    const int q  = l >> 4;
    const int m8 = l >> 3;
    const int n8 = l & 7;

    __shared__ __align__(16) float sA[16*SD];
    __shared__ __align__(16) float sC[128];
    __shared__ __align__(16) float sG[8*SG];
    __shared__ __align__(16) float sW[16*8];
    __shared__ __align__(16) float sV[16*SD];
    __shared__ __align__(16) float sZ[16*SD];
    __shared__ __align__(16) float sP[16*SD];
    __shared__ __align__(16) float sCP[8*SD];
    __shared__ __align__(16) float sU[16*8];
    __shared__ __align__(16) float sPH[16*SPH];
    __shared__ __align__(16) float sSinv[64];

    {
        int r = l >> 2, c4 = l & 3;
        *(float4*)(sA + r*SD + c4*4) = *(const float4*)(gA + r*16 + c4*4);
        if (l < 32) *(float4*)(sC + l*4) = *(const float4*)(gC + l*4);
    }

    float a_row[16];
    #pragma unroll
    for (int k4 = 0; k4 < 4; ++k4) {
        float4 t4 = *(const float4*)(gA + j*16 + k4*4);
        a_row[k4*4+0]=t4.x; a_row[k4*4+1]=t4.y; a_row[k4*4+2]=t4.z; a_row[k4*4+3]=t4.w;
    }
    float4 sxr = *(const float4*)(gSx + j*16 + q*4);
    float  syr = gSy[l];

    WFENCE();

    float c_row[16];
    #pragma unroll
    for (int k4 = 0; k4 < 4; ++k4) {
        float4 cv = *(const float4*)(sC + m8*16 + k4*4);
        c_row[k4*4+0]=cv.x; c_row[k4*4+1]=cv.y; c_row[k4*4+2]=cv.z; c_row[k4*4+3]=cv.w;
    }

    {
        float g1 = 0.f, g2 = 0.f;
        #pragma unroll
        for (int i = 0; i < 16; ++i) {
            g1 += c_row[i]*sA[i*SD + n8];
            g2 += c_row[i]*sA[i*SD + n8 + 8];
        }
        sG[m8*SG + n8]     = g1;
        sG[m8*SG + n8 + 8] = g2;
        ws[WS_G + m8*16 + n8]     = g1;
        ws[WS_G + m8*16 + n8 + 8] = g2;

        if (l < 32) {
            int m = l >> 2, c = l & 3;
            float acc = 0.f;
            #pragma unroll
            for (int i = 0; i < 16; ++i) acc += sC[m*16 + i] * gBm[i*4 + c];
            ws[WS_CB + m*4 + c] = acc;
        }

        float qrow[16];
        #pragma unroll
        for (int k4 = 0; k4 < 4; ++k4) {
            float4 qv = *(const float4*)(gSx + j*16 + k4*4);
            qrow[k4*4+0]=qv.x; qrow[k4*4+1]=qv.y; qrow[k4*4+2]=qv.z; qrow[k4*4+3]=qv.w;
        }
        float w0 = 0.f, w1 = 0.f;
        #pragma unroll
        for (int k = 0; k < 16; ++k) {
            w0 += qrow[k]*sC[(2*q)*16 + k];
            w1 += qrow[k]*sC[(2*q+1)*16 + k];
        }
        sW[j*8 + 2*q]     = w0;
        sW[j*8 + 2*q + 1] = w1;
    }
    WFENCE();

    float sy0 = syr;
    #pragma unroll
    for (int k = 0; k < 16; ++k) sy0 += c_row[k]*sW[k*8 + n8];

    float g_row[16];
    #pragma unroll
    for (int k4 = 0; k4 < 4; ++k4) {
        float4 gv = *(const float4*)(sG + m8*SG + k4*4);
        g_row[k4*4+0]=gv.x; g_row[k4*4+1]=gv.y; g_row[k4*4+2]=gv.z; g_row[k4*4+3]=gv.w;
    }
    float wj0 = sW[j*8 + 2*q], wj1 = sW[j*8 + 2*q + 1];

    float acc_ld2 = 0.f;
    float pr[4];
    int   tconv   = NT-1;

    #pragma unroll 1
    for (int t = 0; t < NT; ++t) {
        float s;
        float v_row[16];

        if (t == 0) {
            float4 p0 = *(const float4*)(gP0 + j*16 + q*4);
            pr[0]=p0.x; pr[1]=p0.y; pr[2]=p0.z; pr[3]=p0.w;
            *(float4*)(sP + j*SD + q*4) = p0;
            WFENCE();
            float p_row[16];
            #pragma unroll
            for (int k4 = 0; k4 < 4; ++k4) {
                float4 pv = *(const float4*)(sP + j*SD + k4*4);
                p_row[k4*4+0]=pv.x; p_row[k4*4+1]=pv.y; p_row[k4*4+2]=pv.z; p_row[k4*4+3]=pv.w;
            }
            float ph0=0.f, ph1=0.f;
            #pragma unroll
            for (int k = 0; k < 16; ++k) {
                ph0 += p_row[k]*sC[(2*q)*16 + k];
                ph1 += p_row[k]*sC[(2*q+1)*16 + k];
            }
            *(float2*)(sPH + j*SPH + 2*q) = make_float2(ph0, ph1);
            WFENCE();
            s = syr;
            #pragma unroll
            for (int k = 0; k < 16; ++k) s += c_row[k]*sPH[k*SPH + n8];
        } else {
            #pragma unroll
            for (int k4 = 0; k4 < 4; ++k4) {
                float4 vv = *(const float4*)(sV + j*SD + k4*4);
                v_row[k4*4+0]=vv.x; v_row[k4*4+1]=vv.y; v_row[k4*4+2]=vv.z; v_row[k4*4+3]=vv.w;
            }
            float u0 = 0.f, u1 = 0.f;
            #pragma unroll
            for (int k4 = 0; k4 < 4; ++k4) {
                float4 ga = *(const float4*)(sG + (2*q)*SG + k4*4);
                float4 gb = *(const float4*)(sG + (2*q+1)*SG + k4*4);
                u0 += v_row[k4*4+0]*ga.x + v_row[k4*4+1]*ga.y
                    + v_row[k4*4+2]*ga.z + v_row[k4*4+3]*ga.w;
                u1 += v_row[k4*4+0]*gb.x + v_row[k4*4+1]*gb.y
                    + v_row[k4*4+2]*gb.z + v_row[k4*4+3]*gb.w;
            }
            *(float2*)(sU + j*8 + 2*q) = make_float2(u0, u1);

            float z0=0.f, z1=0.f, z2=0.f, z3=0.f;
            #pragma unroll
            for (int k4 = 0; k4 < 4; ++k4) {
                float4 a0 = *(const float4*)(sA + (4*q+0)*SD + k4*4);
                float4 a1 = *(const float4*)(sA + (4*q+1)*SD + k4*4);
                float4 a2 = *(const float4*)(sA + (4*q+2)*SD + k4*4);
                float4 a3 = *(const float4*)(sA + (4*q+3)*SD + k4*4);
                z0 += v_row[k4*4+0]*a0.x + v_row[k4*4+1]*a0.y
                    + v_row[k4*4+2]*a0.z + v_row[k4*4+3]*a0.w;
                z1 += v_row[k4*4+0]*a1.x + v_row[k4*4+1]*a1.y
                    + v_row[k4*4+2]*a1.z + v_row[k4*4+3]*a1.w;
                z2 += v_row[k4*4+0]*a2.x + v_row[k4*4+1]*a2.y
                    + v_row[k4*4+2]*a2.z + v_row[k4*4+3]*a2.w;
                z3 += v_row[k4*4+0]*a3.x + v_row[k4*4+1]*a3.y
                    + v_row[k4*4+2]*a3.z + v_row[k4*4+3]*a3.w;
            }
            *(float4*)(sZ + j*SD + q*4) = make_float4(z0,z1,z2,z3);
            WFENCE();

            s = sy0;
            #pragma unroll
            for (int k = 0; k < 16; ++k) s += g_row[k]*sU[k*8 + n8];

            float ph0 = wj0, ph1 = wj1;
            #pragma unroll
            for (int k = 0; k < 16; ++k) {
                float2 uv = *(const float2*)(sU + k*8 + 2*q);
                ph0 += a_row[k]*uv.x;
                ph1 += a_row[k]*uv.y;
            }
            *(float2*)(sPH + j*SPH + 2*q) = make_float2(ph0, ph1);

            float p0=0.f, p1=0.f, p2=0.f, p3=0.f;
            #pragma unroll
            for (int k = 0; k < 16; ++k) {
                float4 zv = *(const float4*)(sZ + k*SD + q*4);
                p0 += a_row[k]*zv.x; p1 += a_row[k]*zv.y;
                p2 += a_row[k]*zv.z; p3 += a_row[k]*zv.w;
            }
            pr[0]=p0+sxr.x; pr[1]=p1+sxr.y; pr[2]=p2+sxr.z; pr[3]=p3+sxr.w;
            *(float4*)(sP + j*SD + q*4) = make_float4(pr[0],pr[1],pr[2],pr[3]);
        }
        WFENCE();

        out[OFF_VY + (size_t)t*64 + l] = s;

        {
            float cp1 = 0.f, cp2 = 0.f;
            #pragma unroll
            for (int i = 0; i < 16; ++i) {
                cp1 += c_row[i]*sP[i*SD + n8];
                cp2 += c_row[i]*sP[i*SD + n8 + 8];
            }
            sCP[m8*SD + n8]     = cp1;
            sCP[m8*SD + n8 + 8] = cp2;
        }

        float sv  = s;
        float ld2 = 0.f;
        #pragma unroll
        for (int p = 0; p < 8; ++p) {
            float app = __shfl(sv, p*9, 64);
            float apn = __shfl(sv, p*8 + n8, 64);
            float amp = __shfl(sv, m8*8 + p, 64);
            float d   = __builtin_amdgcn_rcpf(app);
            d = d * (2.0f - app*d);
            ld2 += __log2f(app);
            float rps  = apn * d;
            float vtop = (n8 == p) ? d          : rps;
            float voth = (n8 == p) ? (-amp * d) : fmaf(-amp, rps, sv);
            sv = (m8 == p) ? vtop : voth;
        }
        acc_ld2 += ld2;

        sSinv[l] = sv;
        ws[t*WS_KSTRIDE + 128 + l] = sv;
        WFENCE();

        float phj[8];
        {
            float4 a0 = *(const float4*)(sPH + j*SPH + 0);
            float4 a1 = *(const float4*)(sPH + j*SPH + 4);
            phj[0]=a0.x; phj[1]=a0.y; phj[2]=a0.z; phj[3]=a0.w;
            phj[4]=a1.x; phj[5]=a1.y; phj[6]=a1.z; phj[7]=a1.w;
        }
        float kk[8] = {0.f,0.f,0.f,0.f,0.f,0.f,0.f,0.f};
        #pragma unroll
        for (int k = 0; k < 8; ++k) {
            float4 s0 = *(const float4*)(sSinv + k*8 + 0);
            float4 s1 = *(const float4*)(sSinv + k*8 + 4);
            kk[0]+=phj[k]*s0.x; kk[1]+=phj[k]*s0.y; kk[2]+=phj[k]*s0.z; kk[3]+=phj[k]*s0.w;
            kk[4]+=phj[k]*s1.x; kk[5]+=phj[k]*s1.y; kk[6]+=phj[k]*s1.z; kk[7]+=phj[k]*s1.w;
        }
        float2 kpair = make_float2(kk[2*q], kk[2*q+1]);
        *(float2*)(ws + t*WS_KSTRIDE + j*8 + 2*q) = kpair;

        float vn0=pr[0], vn1=pr[1], vn2=pr[2], vn3=pr[3];
        #pragma unroll
        for (int m = 0; m < 8; ++m) {
            float4 cv = *(const float4*)(sCP + m*SD + q*4);
            vn0 -= kk[m]*cv.x; vn1 -= kk[m]*cv.y;
            vn2 -= kk[m]*cv.z; vn3 -= kk[m]*cv.w;
        }
        float4 vnq = make_float4(vn0,vn1,vn2,vn3);
        *(float4*)(sV + j*SD + q*4) = vnq;
        *(float4*)(out + OFF_V + ((size_t)t*256 + j*16 + q*4)) = vnq;

        float dmax = 1e9f;
        if (t > 0) {
            float d0 = fabsf(vn0 - v_row[4*q+0]);
            float d1 = fabsf(vn1 - v_row[4*q+1]);
            float d2 = fabsf(vn2 - v_row[4*q+2]);
            float d3 = fabsf(vn3 - v_row[4*q+3]);
            dmax = fmaxf(fmaxf(d0,d1), fmaxf(d2,d3));
        }

        if (__all(dmax <= CONV_EPS) && t < NT-1) {
            tconv = t;
            acc_ld2 += (float)(NT-1 - t) * ld2;
            #pragma unroll 4
            for (int t2 = t+1; t2 < NT; ++t2) {
                ntstore1(out + OFF_VY + (size_t)t2*64 + l, s);
                ntstore4(out + OFF_V + ((size_t)t2*256 + j*16 + q*4), vnq);
                *(float2*)(ws + t2*WS_KSTRIDE + j*8 + 2*q) = kpair;
                ws[t2*WS_KSTRIDE + 128 + l] = sv;
            }
            break;
        }
        WFENCE();
    }

    if (l == 0) {
        ws[WS_LD2]   = acc_ld2;
        ws[WS_TCONV] = __int_as_float(tconv);
    }
}

// mu-step phase K (0..3): consume slot, capture y, refill for TT+4;
// store y rows every 4 steps (lanes 0..31, coalesced 128 B)
#define MU_PHASE(TT, K, KA, KB, SC, YY, UU)                                   \
    do {                                                                      \
        float mub[16];                                                        \
        _Pragma("unroll")                                                     \
        for (int k = 0; k < 16; ++k) mub[k] = lane_bcast(muj, k);             \
        float x_j, yp;                                                        \
        if ((TT) == 0) {                                                      \
            x_j = muj;                                                        \
            float yp0 = 0.f, yp1 = 0.f;                                       \
            _Pragma("unroll")                                                 \
            for (int k = 0; k < 16; k += 2) {                                 \
                yp0 += cn_row[k]*mub[k];                                      \
                yp1 += cn_row[k+1]*mub[k+1];                                  \
            }                                                                 \
            yp = yp0 + yp1;                                                   \
        } else {                                                              \
            float x0 = b_row.x*(UU).x + b_row.y*(UU).y;                       \
            float x1 = b_row.z*(UU).z + b_row.w*(UU).w;                       \
            float y0 = cb.x*(UU).x + cb.y*(UU).y;                             \
            float y1 = cb.z*(UU).z + cb.w*(UU).w;                             \
            _Pragma("unroll")                                                 \
            for (int k = 0; k < 16; k += 2) {                                 \
                x0 += a_row[k]*mub[k];    x1 += a_row[k+1]*mub[k+1];          \
                y0 += gn_row[k]*mub[k];   y1 += gn_row[k+1]*mub[k+1];         \
            }                                                                 \
            x_j = x0 + x1;                                                    \
            yp  = y0 + y1;                                                    \
        }                                                                     \
        float dn = (YY) - yp;                                                 \
        ybuf = ((l >> 3) == (K)) ? yp : ybuf;   /* lanes 8K..8K+7 own row */  \
        float dl[8];                                                          \
        _Pragma("unroll")                                                     \
        for (int m = 0; m < 8; ++m) dl[m] = lane_bcast(dn, m);                \
        float dm = __shfl(dn, m8, 64);                                        \
        float mu_new = x_j                                                    \
            + (KA).x*dl[0] + (KA).y*dl[1] + (KA).z*dl[2] + (KA).w*dl[3]       \
            + (KB).x*dl[4] + (KB).y*dl[5] + (KB).z*dl[6] + (KB).w*dl[7];      \
        muj = mu_new;                                                         \
        if (l < 16) ntstore1(out + OFF_MU + ((size_t)b*NT + (TT))*16 + j, muj); \
        part_acc += (SC) * dm * dn;                                           \
        if ((K) == 3 && l < 32)                                               \
            ntstore1(out + OFF_Y + ((size_t)b*NT + (TT) - 3)*8 + l, ybuf);    \
        {                                                                     \
            const int tp = ((TT)+4 < NT) ? (TT)+4 : NT-1;                     \
            (KA) = *(const float4*)(ws + tp*WS_KSTRIDE + j*8);                \
            (KB) = *(const float4*)(ws + tp*WS_KSTRIDE + j*8 + 4);            \
            (SC) = ws[tp*WS_KSTRIDE + 128 + l];                               \
            (YY) = gy[((size_t)b*NT + tp)*8 + n8];                            \
            (UU) = *(const float4*)(gu + ((size_t)b*NT + tp)*4);              \
        }                                                                     \
    } while (0)

// -- Phase 2 (fused, 256-thr blocks): mu (4 waves = 4 batches) ∥ v-copy
// -- (zero-load contiguous-front periodic fill) ∥ vy-copy. All co-resident.
__launch_bounds__(256)
__global__ void stream_kernel(const float* __restrict__ gy, const float* __restrict__ gu,
                              const float* __restrict__ gmu0, const float* __restrict__ gA,
                              const float* __restrict__ gBm, const float* __restrict__ gC,
                              float* __restrict__ ws, float* __restrict__ out)
{
    const int tid = threadIdx.x;
    const int blk = blockIdx.x;

    if (blk >= MU_BLOCKS) {
        if (blk < MU_BLOCKS + VC_BLOCKS) {
            // v-copy: period 16384 float4/batch; G = 448*256 = 7*16384
            const size_t G = (size_t)VC_BLOCKS * 256;
            const size_t g = (size_t)(blk - MU_BLOCKS) * 256 + tid;
            const nfloat4* src = (const nfloat4*)(out + OFF_V);   // batch 0
            nfloat4* dst = (nfloat4*)(out + OFF_V) + 16384;       // batch 1
            const size_t N4 = (size_t)(NB-1) * 16384;
            const nfloat4 val = src[g & 16383];   // loop-invariant offset
            #pragma unroll 4
            for (size_t i = g; i < N4; i += G)
                __builtin_nontemporal_store(val, dst + i);
        } else {
            // vy-copy: period 4096 float4/batch; G = 64*256 = 4*4096
            const size_t G = (size_t)VYC_BLOCKS * 256;
            const size_t g = (size_t)(blk - MU_BLOCKS - VC_BLOCKS) * 256 + tid;
            const nfloat4* src = (const nfloat4*)(out + OFF_VY);
            nfloat4* dst = (nfloat4*)(out + OFF_VY) + 4096;
            const size_t N4 = (size_t)(NB-1) * 4096;
            const nfloat4 val = src[g & 4095];
            #pragma unroll 4
            for (size_t i = g; i < N4; i += G)
                __builtin_nontemporal_store(val, dst + i);
        }
        return;
    }

    // ---- mu role: wave w handles batch blk*4 + w; 4-deep prefetch ----
    const int l  = tid & 63;
    const int b  = blk*4 + (tid >> 6);
    const int j  = l & 15;
    const int m8 = l >> 3;
    const int n8 = l & 7;

    float a_row[16];
    #pragma unroll
    for (int k4 = 0; k4 < 4; ++k4) {
        float4 t4 = *(const float4*)(gA + j*16 + k4*4);
        a_row[k4*4+0]=t4.x; a_row[k4*4+1]=t4.y; a_row[k4*4+2]=t4.z; a_row[k4*4+3]=t4.w;
    }
    float cn_row[16];
    #pragma unroll
    for (int k4 = 0; k4 < 4; ++k4) {
        float4 cv = *(const float4*)(gC + n8*16 + k4*4);
        cn_row[k4*4+0]=cv.x; cn_row[k4*4+1]=cv.y; cn_row[k4*4+2]=cv.z; cn_row[k4*4+3]=cv.w;
    }
    float gn_row[16];
    #pragma unroll
    for (int k4 = 0; k4 < 4; ++k4) {
        float4 gv = *(const float4*)(ws + WS_G + n8*16 + k4*4);
        gn_row[k4*4+0]=gv.x; gn_row[k4*4+1]=gv.y; gn_row[k4*4+2]=gv.z; gn_row[k4*4+3]=gv.w;
    }
    float4 cb    = *(const float4*)(ws + WS_CB + n8*4);
    float4 b_row = *(const float4*)(gBm + j*4);

    float muj = gmu0[b*16 + j];
    float part_acc = 0.f;
    float ybuf = 0.f;

    float4 kA0, kA1, kA2, kA3;
    float4 kB0, kB1, kB2, kB3;
    float  sc0, sc1, sc2, sc3;
    float  yy0, yy1, yy2, yy3;
    float4 uu0, uu1, uu2, uu3;

#define LOAD_SLOT(N)                                                          \
    kA##N = *(const float4*)(ws + (N)*WS_KSTRIDE + j*8);                      \
    kB##N = *(const float4*)(ws + (N)*WS_KSTRIDE + j*8 + 4);                  \
    sc##N = ws[(N)*WS_KSTRIDE + 128 + l];                                     \
    yy##N = gy[((size_t)b*NT + (N))*8 + n8];                                  \
    uu##N = *(const float4*)(gu + ((size_t)b*NT + (N))*4);
    LOAD_SLOT(0) LOAD_SLOT(1) LOAD_SLOT(2) LOAD_SLOT(3)
#undef LOAD_SLOT

    #pragma unroll 1
    for (int t = 0; t < NT; t += 4) {
        MU_PHASE(t+0, 0, kA0, kB0, sc0, yy0, uu0);
        MU_PHASE(t+1, 1, kA1, kB1, sc1, yy1, uu1);
        MU_PHASE(t+2, 2, kA2, kB2, sc2, yy2, uu2);
        MU_PHASE(t+3, 3, kA3, kB3, sc3, yy3, uu3);
    }

    #pragma unroll
    for (int mask = 32; mask >= 1; mask >>= 1)
        part_acc += __shfl_xor(part_acc, mask, 64);
    if (l == 0) ws[WS_SSQ + b] = part_acc;
}

// ---------------- Phase 3: logp reduction -----------------
__launch_bounds__(256)
__global__ void logp_sum(const float* __restrict__ ws, float* __restrict__ out)
{
    __shared__ float red[256];
    int t = threadIdx.x;
    float sv = 0.f;
    #pragma unroll
    for (int k = 0; k < 8; ++k) sv += ws[WS_SSQ + t + 256*k];
    red[t] = sv;
    __syncthreads();
    #pragma unroll 1
    for (int off = 128; off >= 1; off >>= 1) {
        if (t < off) red[t] += red[t + off];
        __syncthreads();
    }
    if (t == 0) {
        float ld2sum = ws[WS_LD2];
        out[OFF_LOGP] = -0.5f*(14.703016531274762f
                               + 0.6931471805599453f*ld2sum*(1.0f/256.0f)
                               + red[0]*(1.0f/524288.0f));
    }
}

extern "C" void kernel_launch(void* const* d_in, const int* in_sizes, int n_in,
                              void* d_out, int out_size, void* d_ws, size_t ws_size,
                              hipStream_t stream) {
    (void)in_sizes; (void)n_in; (void)out_size; (void)ws_size;
    const float* gy   = (const float*)d_in[0];
    const float* gu   = (const float*)d_in[1];
    const float* gmu0 = (const float*)d_in[2];
    const float* gP0  = (const float*)d_in[3];
    const float* gA   = (const float*)d_in[4];
    const float* gBm  = (const float*)d_in[5];
    const float* gC   = (const float*)d_in[6];
    const float* gSx  = (const float*)d_in[7];
    const float* gSy  = (const float*)d_in[8];
    float* out = (float*)d_out;
    float* ws  = (float*)d_ws;

    hipLaunchKernelGGL(cov_kernel, dim3(1), dim3(64), 0, stream,
                       gP0, gA, gBm, gC, gSx, gSy, out, ws);
    hipLaunchKernelGGL(stream_kernel, dim3(MU_BLOCKS + VC_BLOCKS + VYC_BLOCKS),
                       dim3(256), 0, stream,
                       gy, gu, gmu0, gA, gBm, gC, ws, out);
    hipLaunchKernelGGL(logp_sum, dim3(1), dim3(256), 0, stream, ws, out);
}